// Round 8
// baseline (339.045 us; speedup 1.0000x reference)
//
#include <hip/hip_runtime.h>
#include <hip/hip_bf16.h>
#include <math.h>

#define FIN 35
#define FOUT 128
#define NGRAPHS 512
#define PWA 32          // pass-A panel width (fp16) = 64 B rows, feats 0..31
#define PWB 4           // pass-B panel width (fp16) = 8 B rows, feats 32..34 + pad
#define STRIP1 64       // nodes per block in nu1 (MFMA: 4 waves x 16-row tiles)
#define CHUNK 4096      // edges per block in hist1/scatter1 (R7: 8192 -> 4096, 2x grid)
#define BSHIFT 7        // bucket = dst >> 7 (128 nodes/bucket; R7: was 256)
#define BMASK 127
#define MAXBUCK 1024    // >= nbuck = ceil(N/128) = 782
#define MAXBE 6144      // csr2 LDS edge-staging capacity (24 KB; mean 4092, sigma 64)

#define STRIPM 64       // nodes per block in nu2 (MFMA: 4 waves x 16-row tiles)
#define HROW 130        // h2 LDS row pad (floats) -> conflict-free epilogue
#define NFRAG 48        // nu2 B fragments: 2 passes (hi/lo) x 3 ksteps x 8 ntiles
#define NFRAG1 18       // nu1 B fragments: 2 passes (hi/lo) x 3 ksteps x 3 ntiles

typedef _Float16 half8 __attribute__((ext_vector_type(8)));
typedef _Float16 half4 __attribute__((ext_vector_type(4)));
typedef float f32x4 __attribute__((ext_vector_type(4)));

// ---------- helpers ----------
__device__ __forceinline__ unsigned int enc_f32(float f) {
    unsigned int u = __float_as_uint(f);
    return (u & 0x80000000u) ? ~u : (u | 0x80000000u);
}
__device__ __forceinline__ float dec_f32(unsigned int u) {
    unsigned int b = (u & 0x80000000u) ? (u ^ 0x80000000u) : ~u;
    return __uint_as_float(b);
}

// ---------- CSR build via two-level LDS radix partition (no global atomics) ----------
// R7 rebalance: hist1/scatter1/csr2 were 391-block grids (1.5 blocks/CU) -> latency-
// bound at ~6 waves/CU. Now 782 blocks each (3+/CU), half-size LDS staging.

__global__ __launch_bounds__(256) void hist1_kernel(const int* __restrict__ dst,
                                                    int* __restrict__ counts,
                                                    int E, int nblk1, int nbuck) {
    __shared__ int h[MAXBUCK];
    int t = threadIdx.x;
    h[t] = 0; h[t + 256] = 0; h[t + 512] = 0; h[t + 768] = 0;
    __syncthreads();
    int base = blockIdx.x * CHUNK;
    int end = min(base + CHUNK, E);
    for (int e = base + t; e < end; e += 256)
        atomicAdd(&h[dst[e] >> BSHIFT], 1);
    __syncthreads();
    for (int b = t; b < nbuck; b += 256)
        counts[b * nblk1 + blockIdx.x] = h[b];
}

__global__ void partial_reduce_kernel(const int* __restrict__ v_in, int* __restrict__ partial, int SC) {
    int i = blockIdx.x * 256 + threadIdx.x;
    int v = (i < SC) ? v_in[i] : 0;
    #pragma unroll
    for (int off = 32; off > 0; off >>= 1) v += __shfl_down(v, off, 64);
    __shared__ int w[4];
    if ((threadIdx.x & 63) == 0) w[threadIdx.x >> 6] = v;
    __syncthreads();
    if (threadIdx.x == 0) partial[blockIdx.x] = w[0] + w[1] + w[2] + w[3];
}

// single block, 4 elements/thread: handles NB <= 4096
__global__ void scan_partials_kernel(int* __restrict__ partial, int NB) {
    __shared__ int lds[1024];
    int t = threadIdx.x;
    int v[4];
    int s = 0;
    #pragma unroll
    for (int i = 0; i < 4; ++i) {
        int idx = 4 * t + i;
        v[i] = (idx < NB) ? partial[idx] : 0;
        s += v[i];
    }
    lds[t] = s;
    __syncthreads();
    for (int off = 1; off < 1024; off <<= 1) {
        int tv = (t >= off) ? lds[t - off] : 0;
        __syncthreads();
        lds[t] += tv;
        __syncthreads();
    }
    int excl = lds[t] - s;
    #pragma unroll
    for (int i = 0; i < 4; ++i) {
        int idx = 4 * t + i;
        if (idx < NB) partial[idx] = excl;
        excl += v[i];
    }
}

__global__ void scan_final_kernel(const int* __restrict__ v_in, const int* __restrict__ partial,
                                  int* __restrict__ outx, int SC) {
    __shared__ int lds[256];
    int i = blockIdx.x * 256 + threadIdx.x;
    int v = (i < SC) ? v_in[i] : 0;
    lds[threadIdx.x] = v;
    __syncthreads();
    for (int off = 1; off < 256; off <<= 1) {
        int tv = (threadIdx.x >= off) ? lds[threadIdx.x - off] : 0;
        __syncthreads();
        lds[threadIdx.x] += tv;
        __syncthreads();
    }
    int excl = lds[threadIdx.x] - v + partial[blockIdx.x];
    if (i < SC) {
        outx[i] = excl;
        if (i == SC - 1) outx[SC] = excl + v;
    }
}

// Block-local counting sort in LDS -> streaming coalesced flush (R1 win).
__global__ __launch_bounds__(256) void scatter1_kernel(const int* __restrict__ src,
                                                       const int* __restrict__ dst,
                                                       const int* __restrict__ offs,
                                                       int* __restrict__ ebuf,
                                                       int E, int nblk1, int nbuck) {
    __shared__ int hist[MAXBUCK];
    __shared__ int scn[256];
    __shared__ int gofs[MAXBUCK];        // global base - local start (dest = gofs[b] + p)
    __shared__ int cur[MAXBUCK];
    __shared__ int sv[CHUNK];            // bucket-sorted packed edges (16 KB)
    __shared__ int sd[CHUNK];            // final global destination per slot (16 KB)
    int t = threadIdx.x;
    int base = blockIdx.x * CHUNK;
    int end = min(base + CHUNK, E);

    hist[t] = 0; hist[t + 256] = 0; hist[t + 512] = 0; hist[t + 768] = 0;
    __syncthreads();
    for (int e = base + t; e < end; e += 256)
        atomicAdd(&hist[dst[e] >> BSHIFT], 1);
    __syncthreads();

    int v[4];
    int tot = 0;
    #pragma unroll
    for (int i = 0; i < 4; ++i) {
        v[i] = hist[4 * t + i];
        tot += v[i];
    }
    scn[t] = tot;
    __syncthreads();
    for (int off = 1; off < 256; off <<= 1) {
        int tv = (t >= off) ? scn[t - off] : 0;
        __syncthreads();
        scn[t] += tv;
        __syncthreads();
    }
    int run = scn[t] - tot;              // exclusive local start of bucket 4t
    #pragma unroll
    for (int i = 0; i < 4; ++i) {
        int b = 4 * t + i;
        cur[b] = run;
        gofs[b] = ((b < nbuck) ? offs[b * nblk1 + blockIdx.x] : 0) - run;
        run += v[i];
    }
    __syncthreads();

    for (int e = base + t; e < end; e += 256) {
        int d = dst[e];                  // L1/L2 hit (read in pass 1)
        int b = d >> BSHIFT;
        int p = atomicAdd(&cur[b], 1);
        sv[p] = (src[e] << BSHIFT) | (d & BMASK);
        sd[p] = gofs[b] + p;
    }
    __syncthreads();

    int cnt = end - base;
    for (int k = t; k < cnt; k += 256)
        ebuf[sd[k]] = sv[k];
}

// Level-2: one block per bucket (128 nodes); bucket edges staged in LDS. Builds
// row_ptr AND the src-half split point hsplit[n] (256 bins: node_local x
// (src>=N/2)) so each node's list is [low-src half | high-src half].
__global__ __launch_bounds__(256) void csr2_kernel(const int* __restrict__ ebuf,
                                                   const int* __restrict__ offs,
                                                   int* __restrict__ row_ptr,
                                                   int* __restrict__ hsplit,
                                                   int* __restrict__ esrc,
                                                   int E, int nblk1, int nbuck, int N, int halfN) {
    __shared__ int h[256];
    __shared__ int scn[256];
    __shared__ int cur[256];
    __shared__ int e_sh[MAXBE];
    int b = blockIdx.x;
    int t = threadIdx.x;
    int bstart = offs[b * nblk1];
    int bend = (b + 1 < nbuck) ? offs[(b + 1) * nblk1] : E;
    int cnt = bend - bstart;
    bool fit = (cnt <= MAXBE);

    if (fit)
        for (int k = t; k < cnt; k += 256) e_sh[k] = ebuf[bstart + k];
    h[t] = 0;
    __syncthreads();
    for (int k = t; k < cnt; k += 256) {
        int e = fit ? e_sh[k] : ebuf[bstart + k];
        int bin = ((e & BMASK) << 1) | ((e >> BSHIFT) >= halfN ? 1 : 0);
        atomicAdd(&h[bin], 1);
    }
    __syncthreads();

    int v0 = (t < 128) ? h[2 * t] : 0;
    int v1 = (t < 128) ? h[2 * t + 1] : 0;
    int pair = v0 + v1;
    scn[t] = pair;
    __syncthreads();
    for (int off = 1; off < 256; off <<= 1) {
        int tv = (t >= off) ? scn[t - off] : 0;
        __syncthreads();
        scn[t] += tv;
        __syncthreads();
    }
    int base = bstart + scn[t] - pair;       // exclusive pair prefix
    int node = (b << BSHIFT) + t;
    if (t < 128 && node < N) {
        row_ptr[node] = base;
        hsplit[node] = base + v0;
    }
    if (b == 0 && t == 0) row_ptr[N] = E;
    if (t < 128) {
        cur[2 * t] = base;
        cur[2 * t + 1] = base + v0;
    }
    __syncthreads();

    for (int k = t; k < cnt; k += 256) {
        int e = fit ? e_sh[k] : ebuf[bstart + k];
        int bin = ((e & BMASK) << 1) | ((e >> BSHIFT) >= halfN ? 1 : 0);
        int p = atomicAdd(&cur[bin], 1);
        esrc[p] = e >> BSHIFT;
    }
}

// ---------- repack x[N][35] -> xA[N][32] (64 B rows) + xB[N][4] (8 B rows, pad zero) ----------
__global__ void repack_kernel(const float* __restrict__ x,
                              _Float16* __restrict__ xA, _Float16* __restrict__ xB, int N) {
    int t = blockIdx.x * 256 + threadIdx.x;          // < N*36
    int NA = N * PWA;
    if (t < NA) {
        int n = t >> 5;
        int f = t & 31;
        xA[t] = (_Float16)x[(long long)n * FIN + f];
    } else if (t < NA + N * PWB) {
        int c = t - NA;
        int n = c >> 2;
        int f3 = c & 3;
        float v = (f3 < 3) ? x[(long long)n * FIN + 32 + f3] : 0.0f;
        xB[c] = (_Float16)v;
    }
}

// ---------- two-pass gather (R3 config: best measured; request-rate-floor bound) ----------
__global__ __launch_bounds__(256) void gather2_kernel(const _Float16* __restrict__ pA,
                                                      const _Float16* __restrict__ pB,
                                                      const int* __restrict__ row_ptr,
                                                      const int* __restrict__ hsplit,
                                                      const int* __restrict__ esrc,
                                                      float* __restrict__ spA,
                                                      float* __restrict__ spB,
                                                      int N, int Wtot, int WS) {
    int q = blockIdx.x & 7;
    int m = blockIdx.x >> 3;
    int w = q * WS + m * 256 + threadIdx.x;
    int wend = min((q + 1) * WS, Wtot);
    if (w >= wend) return;
    int NI = N * 8;
    int pass = w / NI;                       // 0 = A1 (low src), 1 = A2 (high src)
    int t = w - pass * NI;
    int n = t >> 3;
    int quad = (t >> 1) & 3;                 // feature octet within the 64 B row
    int q2 = t & 1;                          // sub-list half
    int b = (pass == 0) ? row_ptr[n] : hsplit[n];
    int e = (pass == 0) ? hsplit[n] : row_ptr[n + 1];
    int len = e - b;
    int k0 = b + ((len * q2) >> 1);
    int k1 = b + ((len * (q2 + 1)) >> 1);
    const _Float16* base = pA + (quad << 3);
    const bool doB = (quad == 0);

    float a0[8] = {0,0,0,0,0,0,0,0}, a1[8] = {0,0,0,0,0,0,0,0};
    float a2[8] = {0,0,0,0,0,0,0,0}, a3[8] = {0,0,0,0,0,0,0,0};
    float bb0[4] = {0,0,0,0}, bb1[4] = {0,0,0,0};
    int k = k0;
    for (; k + 4 <= k1; k += 4) {
        int s0 = esrc[k], s1 = esrc[k + 1], s2 = esrc[k + 2], s3 = esrc[k + 3];
        half8 v0 = *(const half8*)(base + ((long long)s0 << 5));
        half8 v1 = *(const half8*)(base + ((long long)s1 << 5));
        half8 v2 = *(const half8*)(base + ((long long)s2 << 5));
        half8 v3 = *(const half8*)(base + ((long long)s3 << 5));
        if (doB) {
            half4 u0 = *(const half4*)(pB + ((long long)s0 << 2));
            half4 u1 = *(const half4*)(pB + ((long long)s1 << 2));
            half4 u2 = *(const half4*)(pB + ((long long)s2 << 2));
            half4 u3 = *(const half4*)(pB + ((long long)s3 << 2));
            #pragma unroll
            for (int i = 0; i < 4; ++i) {
                bb0[i] += (float)u0[i] + (float)u2[i];
                bb1[i] += (float)u1[i] + (float)u3[i];
            }
        }
        #pragma unroll
        for (int i = 0; i < 8; ++i) {
            a0[i] += (float)v0[i];
            a1[i] += (float)v1[i];
            a2[i] += (float)v2[i];
            a3[i] += (float)v3[i];
        }
    }
    for (; k < k1; ++k) {
        int s = esrc[k];
        half8 v = *(const half8*)(base + ((long long)s << 5));
        if (doB) {
            half4 u = *(const half4*)(pB + ((long long)s << 2));
            #pragma unroll
            for (int i = 0; i < 4; ++i) bb0[i] += (float)u[i];
        }
        #pragma unroll
        for (int i = 0; i < 8; ++i) a0[i] += (float)v[i];
    }

    float s[8];
    #pragma unroll
    for (int i = 0; i < 8; ++i) {
        float p = (a0[i] + a1[i]) + (a2[i] + a3[i]);
        p += __shfl_xor(p, 1, 64);           // combine the two q2 halves
        s[i] = p;
    }
    if (q2 == 0) {                           // raw sums, no division
        float* outp = spA + ((long long)pass * N + n) * PWA + (quad << 3);
        float4 r0, r1;
        r0.x = s[0]; r0.y = s[1]; r0.z = s[2]; r0.w = s[3];
        r1.x = s[4]; r1.y = s[5]; r1.z = s[6]; r1.w = s[7];
        *(float4*)outp = r0;
        *(float4*)(outp + 4) = r1;
    }
    if (doB) {
        float bs[4];
        #pragma unroll
        for (int i = 0; i < 4; ++i) {
            float p = bb0[i] + bb1[i];
            p += __shfl_xor(p, 1, 64);       // lanes t and t^1 both have quad==0
            bs[i] = p;
        }
        if (q2 == 0) {
            float4 r;
            r.x = bs[0]; r.y = bs[1]; r.z = bs[2]; r.w = bs[3];
            *(float4*)(spB + (((long long)pass * N + n) << 2)) = r;
        }
    }
}

// ---------- weight prep for nu1 MFMA: fragment-ordered [hi | lo] fp16 split ----------
__global__ void wprep1_kernel(const float* __restrict__ Wl, const float* __restrict__ Wr,
                              _Float16* __restrict__ wfrag) {
    int f = blockIdx.x;        // 0..17
    int l = threadIdx.x;       // 0..63
    int ps = f / 9;
    int rem = f % 9;
    int ks = rem / 3;
    int nt = rem % 3;
    int n = nt * 16 + (l & 15);
    int kb = ks * 32 + ((l >> 4) << 3);
    half8 o;
    #pragma unroll
    for (int e = 0; e < 8; ++e) {
        int k = kb + e;
        float v = 0.0f;
        if (n < FIN) {
            if (k < 35) v = Wl[k * FIN + n];
            else if (k >= 36 && k < 71) v = Wr[(k - 36) * FIN + n];
        }
        _Float16 hi = (_Float16)v;
        o[e] = ps ? (_Float16)(v - (float)hi) : hi;
    }
    *(half8*)(wfrag + ((size_t)f * 64 + l) * 8) = o;
}

// ---------- nu1 via MFMA: h1 = relu((s/deg)@Wl1 + bl1 + x@Wr1) ----------
__global__ __launch_bounds__(256) void nu1_mfma_kernel(const _Float16* __restrict__ xA,
                                                       const _Float16* __restrict__ xB,
                                                       const float* __restrict__ spA,
                                                       const float* __restrict__ spB,
                                                       const int* __restrict__ row_ptr,
                                                       const _Float16* __restrict__ wfrag,
                                                       const float* __restrict__ bl,
                                                       _Float16* __restrict__ h1A,
                                                       _Float16* __restrict__ h1B,
                                                       int N) {
    __shared__ __align__(16) char Ab[STRIP1 * 256];     // 16 KB
    int node0 = blockIdx.x * STRIP1;
    if (node0 >= N) return;
    int nn = min(STRIP1, N - node0);
    long long NL = N;
    const int t = threadIdx.x;
    const int lane = t & 63;
    const int wv = t >> 6;

    // ---- stage A (wave-specialized by 16B-unit group) ----
    {
        const int r = lane;
        const long long node = (long long)node0 + r;
        const bool valid = (r < nn);
        const int sw = r & 7;
        char* rowp = Ab + r * 256;

        if (wv == 0) {                       // units 0..2: k 0..23 = s/deg feats 0..23
            int dg = 1;
            if (valid) dg = row_ptr[node + 1] - row_ptr[node];
            float inv = 1.0f / (float)max(dg, 1);
            #pragma unroll
            for (int u = 0; u < 3; ++u) {
                half8 h = {0,0,0,0,0,0,0,0};
                if (valid) {
                    const float* p = spA + node * 32 + u * 8;
                    const float* q = spA + (NL + node) * 32 + u * 8;
                    float4 p0 = *(const float4*)p;
                    float4 p1 = *(const float4*)(p + 4);
                    float4 q0 = *(const float4*)q;
                    float4 q1 = *(const float4*)(q + 4);
                    h[0] = (_Float16)((p0.x + q0.x) * inv);
                    h[1] = (_Float16)((p0.y + q0.y) * inv);
                    h[2] = (_Float16)((p0.z + q0.z) * inv);
                    h[3] = (_Float16)((p0.w + q0.w) * inv);
                    h[4] = (_Float16)((p1.x + q1.x) * inv);
                    h[5] = (_Float16)((p1.y + q1.y) * inv);
                    h[6] = (_Float16)((p1.z + q1.z) * inv);
                    h[7] = (_Float16)((p1.w + q1.w) * inv);
                }
                *(half8*)(rowp + ((u ^ sw) << 4)) = h;
            }
        } else if (wv == 1) {                // u3: s 24..31; u4: sB/deg + x0..3; u5: x4..11
            int dg = 1;
            if (valid) dg = row_ptr[node + 1] - row_ptr[node];
            float inv = 1.0f / (float)max(dg, 1);
            half8 h3 = {0,0,0,0,0,0,0,0};
            half8 h4 = {0,0,0,0,0,0,0,0};
            half8 h5 = {0,0,0,0,0,0,0,0};
            if (valid) {
                const float* p = spA + node * 32 + 24;
                const float* q = spA + (NL + node) * 32 + 24;
                float4 p0 = *(const float4*)p;
                float4 p1 = *(const float4*)(p + 4);
                float4 q0 = *(const float4*)q;
                float4 q1 = *(const float4*)(q + 4);
                h3[0] = (_Float16)((p0.x + q0.x) * inv);
                h3[1] = (_Float16)((p0.y + q0.y) * inv);
                h3[2] = (_Float16)((p0.z + q0.z) * inv);
                h3[3] = (_Float16)((p0.w + q0.w) * inv);
                h3[4] = (_Float16)((p1.x + q1.x) * inv);
                h3[5] = (_Float16)((p1.y + q1.y) * inv);
                h3[6] = (_Float16)((p1.z + q1.z) * inv);
                h3[7] = (_Float16)((p1.w + q1.w) * inv);
                float4 sb0 = *(const float4*)(spB + (node << 2));
                float4 sb1 = *(const float4*)(spB + ((NL + node) << 2));
                half4 xa0 = *(const half4*)(xA + (node << 5));
                h4[0] = (_Float16)((sb0.x + sb1.x) * inv);
                h4[1] = (_Float16)((sb0.y + sb1.y) * inv);
                h4[2] = (_Float16)((sb0.z + sb1.z) * inv);
                h4[3] = (_Float16)((sb0.w + sb1.w) * inv);    // k35 = 0 (pad sums 0)
                h4[4] = xa0[0]; h4[5] = xa0[1]; h4[6] = xa0[2]; h4[7] = xa0[3];
                half4 xa1 = *(const half4*)(xA + (node << 5) + 4);
                half4 xa2 = *(const half4*)(xA + (node << 5) + 8);
                h5[0] = xa1[0]; h5[1] = xa1[1]; h5[2] = xa1[2]; h5[3] = xa1[3];
                h5[4] = xa2[0]; h5[5] = xa2[1]; h5[6] = xa2[2]; h5[7] = xa2[3];
            }
            *(half8*)(rowp + ((3 ^ sw) << 4)) = h3;
            *(half8*)(rowp + ((4 ^ sw) << 4)) = h4;
            *(half8*)(rowp + ((5 ^ sw) << 4)) = h5;
        } else if (wv == 2) {                // u6..u8: x12..19, x20..27, x28..31 + xB
            half8 h6 = {0,0,0,0,0,0,0,0};
            half8 h7 = {0,0,0,0,0,0,0,0};
            half8 h8 = {0,0,0,0,0,0,0,0};
            if (valid) {
                half4 a0 = *(const half4*)(xA + (node << 5) + 12);
                half4 a1 = *(const half4*)(xA + (node << 5) + 16);
                half4 a2 = *(const half4*)(xA + (node << 5) + 20);
                half4 a3 = *(const half4*)(xA + (node << 5) + 24);
                half4 a4 = *(const half4*)(xA + (node << 5) + 28);
                half4 b4 = *(const half4*)(xB + (node << 2));         // [3] = 0 by repack
                h6[0] = a0[0]; h6[1] = a0[1]; h6[2] = a0[2]; h6[3] = a0[3];
                h6[4] = a1[0]; h6[5] = a1[1]; h6[6] = a1[2]; h6[7] = a1[3];
                h7[0] = a2[0]; h7[1] = a2[1]; h7[2] = a2[2]; h7[3] = a2[3];
                h7[4] = a3[0]; h7[5] = a3[1]; h7[6] = a3[2]; h7[7] = a3[3];
                h8[0] = a4[0]; h8[1] = a4[1]; h8[2] = a4[2]; h8[3] = a4[3];
                h8[4] = b4[0]; h8[5] = b4[1]; h8[6] = b4[2]; h8[7] = b4[3];
            }
            *(half8*)(rowp + ((6 ^ sw) << 4)) = h6;
            *(half8*)(rowp + ((7 ^ sw) << 4)) = h7;
            *(half8*)(rowp + ((8 ^ sw) << 4)) = h8;
        } else {                             // units 9..11: zero pad
            half8 z = {0,0,0,0,0,0,0,0};
            *(half8*)(rowp + ((9  ^ sw) << 4)) = z;
            *(half8*)(rowp + ((10 ^ sw) << 4)) = z;
            *(half8*)(rowp + ((11 ^ sw) << 4)) = z;
        }
    }
    __syncthreads();

    // ---- MFMA: wave owns 16-node m-tile x 48 cols (3 n-tiles) ----
    f32x4 acc[3];
    #pragma unroll
    for (int nt = 0; nt < 3; ++nt) acc[nt] = (f32x4){0.0f, 0.0f, 0.0f, 0.0f};

    const int m0 = wv << 4;
    const int rr = m0 + (lane & 15);
    const int rsw = lane & 7;
    const int g = lane >> 4;
    const char* arow = Ab + rr * 256;

    #pragma unroll
    for (int ps = 0; ps < 2; ++ps) {
        #pragma unroll
        for (int ks = 0; ks < 3; ++ks) {
            half8 af = *(const half8*)(arow + ((((ks << 2) + g) ^ rsw) << 4));
            const _Float16* wp = wfrag + ((size_t)((ps * 3 + ks) * 3) * 64 + lane) * 8;
            #pragma unroll
            for (int nt = 0; nt < 3; ++nt) {
                half8 bf = *(const half8*)(wp + (size_t)nt * 512);
                acc[nt] = __builtin_amdgcn_mfma_f32_16x16x32_f16(af, bf, acc[nt], 0, 0, 0);
            }
        }
    }

    // ---- epilogue: relu, store h1A / h1B (D: col=lane&15, row=(lane>>4)*4+reg) ----
    const int col0 = lane & 15;
    const int rb = m0 + (g << 2);
    #pragma unroll
    for (int nt = 0; nt < 3; ++nt) {
        int col = (nt << 4) + col0;
        float bb = (col < FIN) ? bl[col] : 0.0f;
        #pragma unroll
        for (int q2 = 0; q2 < 4; ++q2) {
            int r = rb + q2;
            if (r < nn) {
                long long node = node0 + r;
                float v = fmaxf(acc[nt][q2] + bb, 0.0f);
                if (col < 32)      h1A[(node << 5) + col] = (_Float16)v;
                else if (col < 35) h1B[(node << 2) + (col - 32)] = (_Float16)v;
                else if (col == 35) h1B[(node << 2) + 3] = (_Float16)0.0f;  // pad
            }
        }
    }
}

// ---------- weight prep for nu2 MFMA: fragment-ordered [hi | lo] fp16 split ----------
__global__ void wprep2_kernel(const float* __restrict__ Wl, const float* __restrict__ Wr,
                              _Float16* __restrict__ wfrag) {
    int f = blockIdx.x;        // 0..47
    int l = threadIdx.x;       // 0..63
    int ps = f / 24;
    int rem = f % 24;
    int ks = rem >> 3;
    int nt = rem & 7;
    int n = nt * 16 + (l & 15);
    int kb = ks * 32 + ((l >> 4) << 3);
    half8 o;
    #pragma unroll
    for (int e = 0; e < 8; ++e) {
        int k = kb + e;
        float v = 0.0f;
        if (k < 35) v = Wl[k * FOUT + n];
        else if (k >= 36 && k < 71) v = Wr[(k - 36) * FOUT + n];
        _Float16 hi = (_Float16)v;
        o[e] = ps ? (_Float16)(v - (float)hi) : hi;
    }
    *(half8*)(wfrag + ((size_t)f * 64 + l) * 8) = o;
}

// ---------- nu2 + pool via MFMA: h2 = (s/deg)@Wl2 + bl2 + h1@Wr2, then graph max ----------
__global__ __launch_bounds__(256) void nu2_pool_mfma_kernel(const _Float16* __restrict__ h1A,
                                                            const _Float16* __restrict__ h1B,
                                                            const float* __restrict__ spA,
                                                            const float* __restrict__ spB,
                                                            const int* __restrict__ row_ptr,
                                                            const _Float16* __restrict__ wfrag,
                                                            const float* __restrict__ bl,
                                                            const int* __restrict__ batch,
                                                            unsigned int* __restrict__ genc,
                                                            int N) {
    __shared__ __align__(16) float h_sh[STRIPM * HROW];   // 33280 B; first 16 KB doubles as A tile
    __shared__ int b_sh[STRIPM];

    int node0 = blockIdx.x * STRIPM;
    if (node0 >= N) return;
    int nn = min(STRIPM, N - node0);
    long long NL = N;

    char* Ab = (char*)h_sh;                  // A tile: [64][128] halves, swizzled 16B units
    const int t = threadIdx.x;
    const int lane = t & 63;
    const int wv = t >> 6;

    // ---- stage A (wave-specialized by kb-unit group: no divergence within a wave) ----
    {
        const int r = lane;                  // local node
        const long long node = (long long)node0 + r;
        const bool valid = (r < nn);
        const int sw = r & 7;
        char* rowp = Ab + r * 256;

        if (wv == 0) {                       // units 0..2: k 0..23 = s/deg
            int dg = 1;
            if (valid) dg = row_ptr[node + 1] - row_ptr[node];
            float inv = 1.0f / (float)max(dg, 1);
            #pragma unroll
            for (int u = 0; u < 3; ++u) {
                half8 h = {0,0,0,0,0,0,0,0};
                if (valid) {
                    const float* p = spA + node * 32 + u * 8;
                    const float* q = spA + (NL + node) * 32 + u * 8;
                    float4 p0 = *(const float4*)p;
                    float4 p1 = *(const float4*)(p + 4);
                    float4 q0 = *(const float4*)q;
                    float4 q1 = *(const float4*)(q + 4);
                    h[0] = (_Float16)((p0.x + q0.x) * inv);
                    h[1] = (_Float16)((p0.y + q0.y) * inv);
                    h[2] = (_Float16)((p0.z + q0.z) * inv);
                    h[3] = (_Float16)((p0.w + q0.w) * inv);
                    h[4] = (_Float16)((p1.x + q1.x) * inv);
                    h[5] = (_Float16)((p1.y + q1.y) * inv);
                    h[6] = (_Float16)((p1.z + q1.z) * inv);
                    h[7] = (_Float16)((p1.w + q1.w) * inv);
                }
                *(half8*)(rowp + ((u ^ sw) << 4)) = h;
            }
        } else if (wv == 1) {                // units 3..5: k 24..47 (s tail, sB + h0..3, h4..11)
            int dg = 1;
            if (valid) dg = row_ptr[node + 1] - row_ptr[node];
            float inv = 1.0f / (float)max(dg, 1);
            half8 h3 = {0,0,0,0,0,0,0,0};
            half8 h4 = {0,0,0,0,0,0,0,0};
            half8 h5 = {0,0,0,0,0,0,0,0};
            if (valid) {
                const float* p = spA + node * 32 + 24;
                const float* q = spA + (NL + node) * 32 + 24;
                float4 p0 = *(const float4*)p;
                float4 p1 = *(const float4*)(p + 4);
                float4 q0 = *(const float4*)q;
                float4 q1 = *(const float4*)(q + 4);
                h3[0] = (_Float16)((p0.x + q0.x) * inv);
                h3[1] = (_Float16)((p0.y + q0.y) * inv);
                h3[2] = (_Float16)((p0.z + q0.z) * inv);
                h3[3] = (_Float16)((p0.w + q0.w) * inv);
                h3[4] = (_Float16)((p1.x + q1.x) * inv);
                h3[5] = (_Float16)((p1.y + q1.y) * inv);
                h3[6] = (_Float16)((p1.z + q1.z) * inv);
                h3[7] = (_Float16)((p1.w + q1.w) * inv);
                float4 sb0 = *(const float4*)(spB + (node << 2));                     // pass-0 half
                float4 sb1 = *(const float4*)(spB + ((NL + node) << 2));              // pass-1 half
                half4 ha = *(const half4*)(h1A + (node << 5));
                h4[0] = (_Float16)((sb0.x + sb1.x) * inv);
                h4[1] = (_Float16)((sb0.y + sb1.y) * inv);
                h4[2] = (_Float16)((sb0.z + sb1.z) * inv);
                h4[3] = (_Float16)((sb0.w + sb1.w) * inv);                            // k35 = 0
                h4[4] = ha[0]; h4[5] = ha[1]; h4[6] = ha[2]; h4[7] = ha[3];
                half4 hb0 = *(const half4*)(h1A + (node << 5) + 4);
                half4 hb1 = *(const half4*)(h1A + (node << 5) + 8);
                h5[0] = hb0[0]; h5[1] = hb0[1]; h5[2] = hb0[2]; h5[3] = hb0[3];
                h5[4] = hb1[0]; h5[5] = hb1[1]; h5[6] = hb1[2]; h5[7] = hb1[3];
            }
            *(half8*)(rowp + ((3 ^ sw) << 4)) = h3;
            *(half8*)(rowp + ((4 ^ sw) << 4)) = h4;
            *(half8*)(rowp + ((5 ^ sw) << 4)) = h5;
        } else if (wv == 2) {                // units 6..8: h12..27, h28..34 + 0
            half8 h6 = {0,0,0,0,0,0,0,0};
            half8 h7 = {0,0,0,0,0,0,0,0};
            half8 h8 = {0,0,0,0,0,0,0,0};
            if (valid) {
                half4 a0 = *(const half4*)(h1A + (node << 5) + 12);
                half4 a1 = *(const half4*)(h1A + (node << 5) + 16);
                half4 a2 = *(const half4*)(h1A + (node << 5) + 20);
                half4 a3 = *(const half4*)(h1A + (node << 5) + 24);
                half4 a4 = *(const half4*)(h1A + (node << 5) + 28);
                half4 b4 = *(const half4*)(h1B + (node << 2));        // [3] = 0 by nu1
                h6[0] = a0[0]; h6[1] = a0[1]; h6[2] = a0[2]; h6[3] = a0[3];
                h6[4] = a1[0]; h6[5] = a1[1]; h6[6] = a1[2]; h6[7] = a1[3];
                h7[0] = a2[0]; h7[1] = a2[1]; h7[2] = a2[2]; h7[3] = a2[3];
                h7[4] = a3[0]; h7[5] = a3[1]; h7[6] = a3[2]; h7[7] = a3[3];
                h8[0] = a4[0]; h8[1] = a4[1]; h8[2] = a4[2]; h8[3] = a4[3];
                h8[4] = b4[0]; h8[5] = b4[1]; h8[6] = b4[2]; h8[7] = b4[3];
            }
            *(half8*)(rowp + ((6 ^ sw) << 4)) = h6;
            *(half8*)(rowp + ((7 ^ sw) << 4)) = h7;
            *(half8*)(rowp + ((8 ^ sw) << 4)) = h8;
        } else {                             // units 9..11: zero pad; stage batch ids
            half8 z = {0,0,0,0,0,0,0,0};
            *(half8*)(rowp + ((9  ^ sw) << 4)) = z;
            *(half8*)(rowp + ((10 ^ sw) << 4)) = z;
            *(half8*)(rowp + ((11 ^ sw) << 4)) = z;
            if (lane < nn) b_sh[lane] = batch[node0 + lane];
        }
    }
    __syncthreads();

    // ---- MFMA: each wave computes its 16-node m-tile x all 128 feats ----
    f32x4 acc[8];
    #pragma unroll
    for (int nt = 0; nt < 8; ++nt) acc[nt] = (f32x4){0.0f, 0.0f, 0.0f, 0.0f};

    const int m0 = wv << 4;
    const int rr = m0 + (lane & 15);
    const int rsw = lane & 7;                // == rr & 7 since m0 % 16 == 0
    const int g = lane >> 4;
    const char* arow = Ab + rr * 256;

    #pragma unroll
    for (int ps = 0; ps < 2; ++ps) {
        #pragma unroll
        for (int ks = 0; ks < 3; ++ks) {
            half8 af = *(const half8*)(arow + ((((ks << 2) + g) ^ rsw) << 4));
            const _Float16* wp = wfrag + ((size_t)((ps * 3 + ks) << 3) * 64 + lane) * 8;
            #pragma unroll
            for (int nt = 0; nt < 8; ++nt) {
                half8 bf = *(const half8*)(wp + (size_t)nt * 512);
                acc[nt] = __builtin_amdgcn_mfma_f32_16x16x32_f16(af, bf, acc[nt], 0, 0, 0);
            }
        }
    }
    __syncthreads();                         // A tile dead; reuse LDS for h2

    // ---- epilogue: bias + stage h2, then boundary-walk segment max ----
    const int col = lane & 15;
    const int rbase = m0 + (g << 2);         // D row = (lane>>4)*4 + reg   [m89-verified]
    #pragma unroll
    for (int nt = 0; nt < 8; ++nt) {
        float bb = bl[(nt << 4) + col];
        #pragma unroll
        for (int q2 = 0; q2 < 4; ++q2)
            h_sh[(rbase + q2) * HROW + (nt << 4) + col] = acc[nt][q2] + bb;
    }
    __syncthreads();

    const int j = t & 127;
    const int hh = t >> 7;
    int nl = hh << 5;
    int nend = min(nl + 32, nn);
    if (nl < nend) {
        int curg = b_sh[nl];
        float mx = -INFINITY;
        for (; nl < nend; ++nl) {
            float v = h_sh[nl * HROW + j];
            int gb = b_sh[nl];               // wave-uniform
            if (gb != curg) {
                atomicMax(&genc[curg * FOUT + j], enc_f32(mx));
                curg = gb;
                mx = v;
            } else {
                mx = fmaxf(mx, v);
            }
        }
        atomicMax(&genc[curg * FOUT + j], enc_f32(mx));
    }
}

// ---------- head: one block (128 threads) per graph ----------
__global__ void head_kernel(const unsigned int* __restrict__ genc,
                            const float* __restrict__ Wg1, const float* __restrict__ bg1,
                            const float* __restrict__ Wg2, const float* __restrict__ bg2,
                            const float* __restrict__ Wo,  const float* __restrict__ bo,
                            float* __restrict__ out) {
    __shared__ float a[FOUT];
    __shared__ float c[FOUT];
    __shared__ float red[2];
    int g = blockIdx.x;
    int j = threadIdx.x;

    a[j] = dec_f32(genc[g * FOUT + j]);
    __syncthreads();

    float acc = bg1[j];
    #pragma unroll 8
    for (int i = 0; i < FOUT; ++i) acc = fmaf(a[i], Wg1[i * FOUT + j], acc);
    c[j] = fmaxf(acc, 0.0f);
    __syncthreads();

    acc = bg2[j];
    #pragma unroll 8
    for (int i = 0; i < FOUT; ++i) acc = fmaf(c[i], Wg2[i * FOUT + j], acc);
    float t = fmaxf(acc, 0.0f) * Wo[j];

    #pragma unroll
    for (int off = 32; off > 0; off >>= 1) t += __shfl_down(t, off, 64);
    if ((threadIdx.x & 63) == 0) red[threadIdx.x >> 6] = t;
    __syncthreads();
    if (threadIdx.x == 0) out[g] = red[0] + red[1] + bo[0];
}

// ---------- launch ----------
extern "C" void kernel_launch(void* const* d_in, const int* in_sizes, int n_in,
                              void* d_out, int out_size, void* d_ws, size_t ws_size,
                              hipStream_t stream) {
    const float* x    = (const float*)d_in[0];
    const int*   ei   = (const int*)  d_in[1];
    const int*   batch= (const int*)  d_in[2];
    const float* Wl1  = (const float*)d_in[3];
    const float* bl1  = (const float*)d_in[4];
    const float* Wr1  = (const float*)d_in[5];
    const float* Wl2  = (const float*)d_in[6];
    const float* bl2  = (const float*)d_in[7];
    const float* Wr2  = (const float*)d_in[8];
    const float* Wg1  = (const float*)d_in[9];
    const float* bg1  = (const float*)d_in[10];
    const float* Wg2  = (const float*)d_in[11];
    const float* bg2  = (const float*)d_in[12];
    const float* Wo   = (const float*)d_in[13];
    const float* bo   = (const float*)d_in[14];
    float* out = (float*)d_out;

    const int N = in_sizes[0] / FIN;
    const int E = in_sizes[1] / 2;
    const int* src = ei;
    const int* dst = ei + E;
    const int halfN = N >> 1;

    const int nblk1 = (E + CHUNK - 1) / CHUNK;          // 782
    const int nbuck = (N + BMASK) >> BSHIFT;            // 782 (<= MAXBUCK)
    const int SC = nbuck * nblk1;                       // 611,524
    const int NB2 = (SC + 255) / 256;                   // 2389 (<= 4096)

    // workspace layout (lifetimes: ebuf -> h1A/h1B/wfrag/wfrag1)
    char* ws = (char*)d_ws;
    size_t off = 0;
    auto alloc = [&](size_t bytes) { char* p = ws + off; off += (bytes + 255) & ~255ull; return p; };
    int*          counts  = (int*)alloc((size_t)SC * 4);
    int*          offs    = (int*)alloc((size_t)(SC + 1) * 4);
    int*          partial = (int*)alloc(4096 * 4);
    int*          row_ptr = (int*)alloc((size_t)(N + 1) * 4);
    int*          hsplit  = (int*)alloc((size_t)N * 4);
    int*          esrc    = (int*)alloc((size_t)E * 4);
    char*         regionA = (char*)alloc((size_t)E * 4);          // ebuf (12.8 MB) then h1A+h1B+wfrags
    _Float16*     xA      = (_Float16*)alloc((size_t)N * PWA * 2);
    _Float16*     xB      = (_Float16*)alloc((size_t)N * PWB * 2);
    float*        spA     = (float*)alloc((size_t)2 * N * PWA * 4);  // raw A sums, halves 0/1 (25.6 MB)
    float*        spB     = (float*)alloc((size_t)2 * N * PWB * 4);  // raw B sums, halves 0/1 (3.2 MB)
    unsigned int* genc    = (unsigned int*)alloc((size_t)NGRAPHS * FOUT * 4);
    int*       ebuf   = (int*)regionA;
    _Float16*  h1A    = (_Float16*)regionA;
    _Float16*  h1B    = (_Float16*)(regionA + (size_t)N * PWA * 2);
    _Float16*  wfrag  = (_Float16*)(regionA + (size_t)N * (PWA + PWB) * 2);            // 48 KB
    _Float16*  wfrag1 = (_Float16*)(regionA + (size_t)N * (PWA + PWB) * 2 + NFRAG * 1024); // 18 KB
    (void)ws_size; (void)n_in; (void)out_size;

    const int BS = 256;
    const int Wtot = N * 16;                             // 8N per pass x 2 passes (B folded in)
    int WS = ((Wtot / 8 + BS - 1) / BS) * BS;            // per-XCD share, 256-aligned
    const int bpx = WS / BS;                             // blocks per XCD share
    const int rpb = (N * 36 + BS - 1) / BS;              // repack items = N*(32+4)
    int nu1b = (N + STRIP1 - 1) / STRIP1;
    int nu2b = (N + STRIPM - 1) / STRIPM;

    // ---- CSR build (LDS radix, no global atomics; reused by both conv layers) ----
    hipLaunchKernelGGL(hist1_kernel, dim3(nblk1), dim3(BS), 0, stream, dst, counts, E, nblk1, nbuck);
    hipLaunchKernelGGL(partial_reduce_kernel, dim3(NB2), dim3(BS), 0, stream, counts, partial, SC);
    hipLaunchKernelGGL(scan_partials_kernel, dim3(1), dim3(1024), 0, stream, partial, NB2);
    hipLaunchKernelGGL(scan_final_kernel, dim3(NB2), dim3(BS), 0, stream, counts, partial, offs, SC);
    hipLaunchKernelGGL(scatter1_kernel, dim3(nblk1), dim3(BS), 0, stream, src, dst, offs, ebuf, E, nblk1, nbuck);
    hipLaunchKernelGGL(csr2_kernel, dim3(nbuck), dim3(BS), 0, stream,
                       ebuf, offs, row_ptr, hsplit, esrc, E, nblk1, nbuck, N, halfN);

    // ---- weight fragments (after csr2: wfrag region aliases dead ebuf tail) ----
    hipLaunchKernelGGL(wprep2_kernel, dim3(NFRAG), dim3(64), 0, stream, Wl2, Wr2, wfrag);
    hipLaunchKernelGGL(wprep1_kernel, dim3(NFRAG1), dim3(64), 0, stream, Wl1, Wr1, wfrag1);

    // ---- conv1: fp16 repack -> two-pass gather (B folded in) -> MFMA node update ----
    hipLaunchKernelGGL(repack_kernel, dim3(rpb), dim3(BS), 0, stream, x, xA, xB, N);
    hipLaunchKernelGGL(gather2_kernel, dim3(8 * bpx), dim3(BS), 0, stream,
                       xA, xB, row_ptr, hsplit, esrc, spA, spB, N, Wtot, WS);
    hipLaunchKernelGGL(nu1_mfma_kernel, dim3(nu1b), dim3(BS), 0, stream,
                       xA, xB, spA, spB, row_ptr, wfrag1, bl1, h1A, h1B, N);

    // ---- conv2: two-pass gather over h1 -> MFMA node update + pool ----
    hipLaunchKernelGGL(gather2_kernel, dim3(8 * bpx), dim3(BS), 0, stream,
                       h1A, h1B, row_ptr, hsplit, esrc, spA, spB, N, Wtot, WS);
    hipMemsetAsync(genc, 0, (size_t)NGRAPHS * FOUT * 4, stream);
    hipLaunchKernelGGL(nu2_pool_mfma_kernel, dim3(nu2b), dim3(BS), 0, stream,
                       h1A, h1B, spA, spB, row_ptr, wfrag, bl2, batch, genc, N);

    // ---- head ----
    hipLaunchKernelGGL(head_kernel, dim3(NGRAPHS), dim3(FOUT), 0, stream,
                       genc, Wg1, bg1, Wg2, bg2, Wo, bo, out);
}

// Round 9
// 306.614 us; speedup vs baseline: 1.1058x; 1.1058x over previous
//
#include <hip/hip_runtime.h>
#include <hip/hip_bf16.h>
#include <math.h>

#define FIN 35
#define FOUT 128
#define NGRAPHS 512
#define PWA 32          // pass-A panel width (fp16) = 64 B rows, feats 0..31
#define PWB 4           // pass-B panel width (fp16) = 8 B rows, feats 32..34 + pad
#define STRIP1 64       // nodes per block in nu1 (MFMA: 4 waves x 16-row tiles)
#define CHUNK 8192      // edges per block in hist1/scatter1 (R7 config: best measured)
#define MAXBUCK 512     // >= ceil(N/256)
#define MAXBE 12288     // csr2 LDS edge-staging capacity (48 KB)

#define STRIPM 64       // nodes per block in nu2 (MFMA: 4 waves x 16-row tiles)
#define HROW 130        // h2 LDS row pad (floats) -> conflict-free epilogue
#define NFRAG 48        // nu2 B fragments: 2 passes (hi/lo) x 3 ksteps x 8 ntiles
#define NFRAG1 18       // nu1 B fragments: 2 passes (hi/lo) x 3 ksteps x 3 ntiles
#define GZBLK 48        // prep_kernel blocks dedicated to genc zeroing

typedef _Float16 half8 __attribute__((ext_vector_type(8)));
typedef _Float16 half4 __attribute__((ext_vector_type(4)));
typedef float f32x4 __attribute__((ext_vector_type(4)));

// ---------- helpers ----------
__device__ __forceinline__ unsigned int enc_f32(float f) {
    unsigned int u = __float_as_uint(f);
    return (u & 0x80000000u) ? ~u : (u | 0x80000000u);
}
__device__ __forceinline__ float dec_f32(unsigned int u) {
    unsigned int b = (u & 0x80000000u) ? (u ^ 0x80000000u) : ~u;
    return __uint_as_float(b);
}

// ---------- CSR build via two-level LDS radix partition (no global atomics) ----------
// R8 post-mortem: all chain blocks are co-resident (grid <= LDS capacity), so kernel
// time == single-block latency (scatter1@R8: VALUBusy 3.3%, nothing saturated).
// R8's grid-doubling was the wrong lever (regressed); per-block wave count is the
// right one: 1024-thread hist1, 512-thread scatter1/csr2 -> 2-4x shorter serial
// dependency chains per thread, 2x waves/CU at unchanged LDS.

__global__ __launch_bounds__(1024) void hist1_kernel(const int* __restrict__ dst,
                                                     int* __restrict__ counts,
                                                     int E, int nblk1, int nbuck) {
    __shared__ int h[MAXBUCK];
    int t = threadIdx.x;
    if (t < MAXBUCK) h[t] = 0;
    __syncthreads();
    int base = blockIdx.x * CHUNK;
    int end = min(base + CHUNK, E);
    for (int e = base + t; e < end; e += 1024)
        atomicAdd(&h[dst[e] >> 8], 1);
    __syncthreads();
    for (int b = t; b < nbuck; b += 1024)
        counts[b * nblk1 + blockIdx.x] = h[b];
}

__global__ void partial_reduce_kernel(const int* __restrict__ v_in, int* __restrict__ partial, int SC) {
    int i = blockIdx.x * 256 + threadIdx.x;
    int v = (i < SC) ? v_in[i] : 0;
    #pragma unroll
    for (int off = 32; off > 0; off >>= 1) v += __shfl_down(v, off, 64);
    __shared__ int w[4];
    if ((threadIdx.x & 63) == 0) w[threadIdx.x >> 6] = v;
    __syncthreads();
    if (threadIdx.x == 0) partial[blockIdx.x] = w[0] + w[1] + w[2] + w[3];
}

__global__ void scan_partials_kernel(int* __restrict__ partial, int NB) {
    __shared__ int lds[1024];
    int t = threadIdx.x;
    int v = (t < NB) ? partial[t] : 0;
    lds[t] = v;
    __syncthreads();
    for (int off = 1; off < 1024; off <<= 1) {
        int tv = (t >= off) ? lds[t - off] : 0;
        __syncthreads();
        lds[t] += tv;
        __syncthreads();
    }
    if (t < NB) partial[t] = lds[t] - v;   // exclusive
}

__global__ void scan_final_kernel(const int* __restrict__ v_in, const int* __restrict__ partial,
                                  int* __restrict__ outx, int SC) {
    __shared__ int lds[256];
    int i = blockIdx.x * 256 + threadIdx.x;
    int v = (i < SC) ? v_in[i] : 0;
    lds[threadIdx.x] = v;
    __syncthreads();
    for (int off = 1; off < 256; off <<= 1) {
        int tv = (threadIdx.x >= off) ? lds[threadIdx.x - off] : 0;
        __syncthreads();
        lds[threadIdx.x] += tv;
        __syncthreads();
    }
    int excl = lds[threadIdx.x] - v + partial[blockIdx.x];
    if (i < SC) {
        outx[i] = excl;
        if (i == SC - 1) outx[SC] = excl + v;
    }
}

// Block-local counting sort in LDS -> streaming coalesced flush (R1 win).
// 512 threads: 16 edges/thread per pass (was 32); scan phase stays 256-wide.
__global__ __launch_bounds__(512) void scatter1_kernel(const int* __restrict__ src,
                                                       const int* __restrict__ dst,
                                                       const int* __restrict__ offs,
                                                       int* __restrict__ ebuf,
                                                       int E, int nblk1, int nbuck) {
    __shared__ int hist[MAXBUCK];
    __shared__ int scn[512];
    __shared__ int gofs[MAXBUCK];        // global base - local start (dest = gofs[b] + p)
    __shared__ int cur[MAXBUCK];
    __shared__ int sv[CHUNK];            // bucket-sorted packed edges (32 KB)
    __shared__ int sd[CHUNK];            // final global destination per slot (32 KB)
    int t = threadIdx.x;
    int base = blockIdx.x * CHUNK;
    int end = min(base + CHUNK, E);

    if (t < MAXBUCK) hist[t] = 0;
    __syncthreads();
    for (int e = base + t; e < end; e += 512)
        atomicAdd(&hist[dst[e] >> 8], 1);
    __syncthreads();

    int v0 = (t < 256) ? hist[2 * t] : 0;
    int v1 = (t < 256) ? hist[2 * t + 1] : 0;
    int pair = v0 + v1;
    scn[t] = (t < 256) ? pair : 0;
    __syncthreads();
    for (int off = 1; off < 256; off <<= 1) {
        int tv = (t >= off) ? scn[t - off] : 0;
        __syncthreads();
        scn[t] += tv;
        __syncthreads();
    }
    if (t < 256) {
        int ex = scn[t] - pair;          // exclusive local start of bucket 2t
        cur[2 * t] = ex;
        cur[2 * t + 1] = ex + v0;
        int b0 = 2 * t, b1 = 2 * t + 1;
        gofs[b0] = ((b0 < nbuck) ? offs[b0 * nblk1 + blockIdx.x] : 0) - ex;
        gofs[b1] = ((b1 < nbuck) ? offs[b1 * nblk1 + blockIdx.x] : 0) - (ex + v0);
    }
    __syncthreads();

    for (int e = base + t; e < end; e += 512) {
        int d = dst[e];                  // L1/L2 hit (read in pass 1)
        int b = d >> 8;
        int p = atomicAdd(&cur[b], 1);
        sv[p] = (src[e] << 8) | (d & 255);
        sd[p] = gofs[b] + p;
    }
    __syncthreads();

    int cnt = end - base;
    for (int k = t; k < cnt; k += 512)
        ebuf[sd[k]] = sv[k];
}

// Level-2: one block per bucket; bucket edges staged in LDS. Builds row_ptr AND the
// src-half split point hsplit[n] (512 bins: node_local x (src>=N/2)). 512 threads.
__global__ __launch_bounds__(512) void csr2_kernel(const int* __restrict__ ebuf,
                                                   const int* __restrict__ offs,
                                                   int* __restrict__ row_ptr,
                                                   int* __restrict__ hsplit,
                                                   int* __restrict__ esrc,
                                                   int E, int nblk1, int nbuck, int N, int halfN) {
    __shared__ int h[512];
    __shared__ int scn[512];
    __shared__ int cur[512];
    __shared__ int e_sh[MAXBE];
    int b = blockIdx.x;
    int t = threadIdx.x;
    int bstart = offs[b * nblk1];
    int bend = (b + 1 < nbuck) ? offs[(b + 1) * nblk1] : E;
    int cnt = bend - bstart;
    bool fit = (cnt <= MAXBE);

    if (fit)
        for (int k = t; k < cnt; k += 512) e_sh[k] = ebuf[bstart + k];
    h[t] = 0;
    __syncthreads();
    for (int k = t; k < cnt; k += 512) {
        int e = fit ? e_sh[k] : ebuf[bstart + k];
        int bin = ((e & 255) << 1) | ((e >> 8) >= halfN ? 1 : 0);
        atomicAdd(&h[bin], 1);
    }
    __syncthreads();

    int v0 = (t < 256) ? h[2 * t] : 0;
    int v1 = (t < 256) ? h[2 * t + 1] : 0;
    int pair = v0 + v1;
    scn[t] = (t < 256) ? pair : 0;
    __syncthreads();
    for (int off = 1; off < 256; off <<= 1) {
        int tv = (t >= off) ? scn[t - off] : 0;
        __syncthreads();
        scn[t] += tv;
        __syncthreads();
    }
    if (t < 256) {
        int base = bstart + scn[t] - pair;   // exclusive pair prefix
        int node = (b << 8) + t;
        if (node < N) {
            row_ptr[node] = base;
            hsplit[node] = base + v0;
        }
        cur[2 * t] = base;
        cur[2 * t + 1] = base + v0;
    }
    if (b == 0 && t == 0) row_ptr[N] = E;
    __syncthreads();

    for (int k = t; k < cnt; k += 512) {
        int e = fit ? e_sh[k] : ebuf[bstart + k];
        int bin = ((e & 255) << 1) | ((e >> 8) >= halfN ? 1 : 0);
        int p = atomicAdd(&cur[bin], 1);
        esrc[p] = e >> 8;
    }
}

// ---------- repack x[N][35] -> xA[N][32] (64 B rows) + xB[N][4] (8 B rows, pad zero) ----------
__global__ void repack_kernel(const float* __restrict__ x,
                              _Float16* __restrict__ xA, _Float16* __restrict__ xB, int N) {
    int t = blockIdx.x * 256 + threadIdx.x;          // < N*36
    int NA = N * PWA;
    if (t < NA) {
        int n = t >> 5;
        int f = t & 31;
        xA[t] = (_Float16)x[(long long)n * FIN + f];
    } else if (t < NA + N * PWB) {
        int c = t - NA;
        int n = c >> 2;
        int f3 = c & 3;
        float v = (f3 < 3) ? x[(long long)n * FIN + 32 + f3] : 0.0f;
        xB[c] = (_Float16)v;
    }
}

// ---------- two-pass gather (R3 config: best measured; request-rate-floor bound) ----------
__global__ __launch_bounds__(256) void gather2_kernel(const _Float16* __restrict__ pA,
                                                      const _Float16* __restrict__ pB,
                                                      const int* __restrict__ row_ptr,
                                                      const int* __restrict__ hsplit,
                                                      const int* __restrict__ esrc,
                                                      float* __restrict__ spA,
                                                      float* __restrict__ spB,
                                                      int N, int Wtot, int WS) {
    int q = blockIdx.x & 7;
    int m = blockIdx.x >> 3;
    int w = q * WS + m * 256 + threadIdx.x;
    int wend = min((q + 1) * WS, Wtot);
    if (w >= wend) return;
    int NI = N * 8;
    int pass = w / NI;                       // 0 = A1 (low src), 1 = A2 (high src)
    int t = w - pass * NI;
    int n = t >> 3;
    int quad = (t >> 1) & 3;                 // feature octet within the 64 B row
    int q2 = t & 1;                          // sub-list half
    int b = (pass == 0) ? row_ptr[n] : hsplit[n];
    int e = (pass == 0) ? hsplit[n] : row_ptr[n + 1];
    int len = e - b;
    int k0 = b + ((len * q2) >> 1);
    int k1 = b + ((len * (q2 + 1)) >> 1);
    const _Float16* base = pA + (quad << 3);
    const bool doB = (quad == 0);

    float a0[8] = {0,0,0,0,0,0,0,0}, a1[8] = {0,0,0,0,0,0,0,0};
    float a2[8] = {0,0,0,0,0,0,0,0}, a3[8] = {0,0,0,0,0,0,0,0};
    float bb0[4] = {0,0,0,0}, bb1[4] = {0,0,0,0};
    int k = k0;
    for (; k + 4 <= k1; k += 4) {
        int s0 = esrc[k], s1 = esrc[k + 1], s2 = esrc[k + 2], s3 = esrc[k + 3];
        half8 v0 = *(const half8*)(base + ((long long)s0 << 5));
        half8 v1 = *(const half8*)(base + ((long long)s1 << 5));
        half8 v2 = *(const half8*)(base + ((long long)s2 << 5));
        half8 v3 = *(const half8*)(base + ((long long)s3 << 5));
        if (doB) {
            half4 u0 = *(const half4*)(pB + ((long long)s0 << 2));
            half4 u1 = *(const half4*)(pB + ((long long)s1 << 2));
            half4 u2 = *(const half4*)(pB + ((long long)s2 << 2));
            half4 u3 = *(const half4*)(pB + ((long long)s3 << 2));
            #pragma unroll
            for (int i = 0; i < 4; ++i) {
                bb0[i] += (float)u0[i] + (float)u2[i];
                bb1[i] += (float)u1[i] + (float)u3[i];
            }
        }
        #pragma unroll
        for (int i = 0; i < 8; ++i) {
            a0[i] += (float)v0[i];
            a1[i] += (float)v1[i];
            a2[i] += (float)v2[i];
            a3[i] += (float)v3[i];
        }
    }
    for (; k < k1; ++k) {
        int s = esrc[k];
        half8 v = *(const half8*)(base + ((long long)s << 5));
        if (doB) {
            half4 u = *(const half4*)(pB + ((long long)s << 2));
            #pragma unroll
            for (int i = 0; i < 4; ++i) bb0[i] += (float)u[i];
        }
        #pragma unroll
        for (int i = 0; i < 8; ++i) a0[i] += (float)v[i];
    }

    float s[8];
    #pragma unroll
    for (int i = 0; i < 8; ++i) {
        float p = (a0[i] + a1[i]) + (a2[i] + a3[i]);
        p += __shfl_xor(p, 1, 64);           // combine the two q2 halves
        s[i] = p;
    }
    if (q2 == 0) {                           // raw sums, no division
        float* outp = spA + ((long long)pass * N + n) * PWA + (quad << 3);
        float4 r0, r1;
        r0.x = s[0]; r0.y = s[1]; r0.z = s[2]; r0.w = s[3];
        r1.x = s[4]; r1.y = s[5]; r1.z = s[6]; r1.w = s[7];
        *(float4*)outp = r0;
        *(float4*)(outp + 4) = r1;
    }
    if (doB) {
        float bs[4];
        #pragma unroll
        for (int i = 0; i < 4; ++i) {
            float p = bb0[i] + bb1[i];
            p += __shfl_xor(p, 1, 64);       // lanes t and t^1 both have quad==0
            bs[i] = p;
        }
        if (q2 == 0) {
            float4 r;
            r.x = bs[0]; r.y = bs[1]; r.z = bs[2]; r.w = bs[3];
            *(float4*)(spB + (((long long)pass * N + n) << 2)) = r;
        }
    }
}

// ---------- fused prep: nu2 wfrag (blocks 0..47), nu1 wfrag1 (48..65), genc zero ----------
// B rows nu2 (K=96): 0..34 = Wl2, 35 = 0, 36..70 = Wr2, 71..95 = 0.
// B rows nu1: same layout with Wl1/Wr1 (35 cols; cols >= 35 zero).
// pass 0 = fp16(w), pass 1 = fp16(w - fp16(w)) -> two MFMA accumulations, fp32-exact.
__global__ void prep_kernel(const float* __restrict__ Wl2, const float* __restrict__ Wr2,
                            const float* __restrict__ Wl1, const float* __restrict__ Wr1,
                            _Float16* __restrict__ wfrag, _Float16* __restrict__ wfrag1,
                            unsigned int* __restrict__ genc) {
    int f = blockIdx.x;
    int l = threadIdx.x;       // 0..63
    if (f < NFRAG) {           // nu2 fragments
        int ps = f / 24;
        int rem = f % 24;
        int ks = rem >> 3;
        int nt = rem & 7;
        int n = nt * 16 + (l & 15);
        int kb = ks * 32 + ((l >> 4) << 3);
        half8 o;
        #pragma unroll
        for (int e = 0; e < 8; ++e) {
            int k = kb + e;
            float v = 0.0f;
            if (k < 35) v = Wl2[k * FOUT + n];
            else if (k >= 36 && k < 71) v = Wr2[(k - 36) * FOUT + n];
            _Float16 hi = (_Float16)v;
            o[e] = ps ? (_Float16)(v - (float)hi) : hi;
        }
        *(half8*)(wfrag + ((size_t)f * 64 + l) * 8) = o;
    } else if (f < NFRAG + NFRAG1) {    // nu1 fragments
        int f1 = f - NFRAG;
        int ps = f1 / 9;
        int rem = f1 % 9;
        int ks = rem / 3;
        int nt = rem % 3;
        int n = nt * 16 + (l & 15);
        int kb = ks * 32 + ((l >> 4) << 3);
        half8 o;
        #pragma unroll
        for (int e = 0; e < 8; ++e) {
            int k = kb + e;
            float v = 0.0f;
            if (n < FIN) {
                if (k < 35) v = Wl1[k * FIN + n];
                else if (k >= 36 && k < 71) v = Wr1[(k - 36) * FIN + n];
            }
            _Float16 hi = (_Float16)v;
            o[e] = ps ? (_Float16)(v - (float)hi) : hi;
        }
        *(half8*)(wfrag1 + ((size_t)f1 * 64 + l) * 8) = o;
    } else {                            // zero genc (replaces hipMemsetAsync)
        int idx = (f - NFRAG - NFRAG1) * 64 + l;
        for (int i = idx; i < NGRAPHS * FOUT; i += GZBLK * 64)
            genc[i] = 0u;
    }
}

// ---------- nu1 via MFMA: h1 = relu((s/deg)@Wl1 + bl1 + x@Wr1) ----------
__global__ __launch_bounds__(256) void nu1_mfma_kernel(const _Float16* __restrict__ xA,
                                                       const _Float16* __restrict__ xB,
                                                       const float* __restrict__ spA,
                                                       const float* __restrict__ spB,
                                                       const int* __restrict__ row_ptr,
                                                       const _Float16* __restrict__ wfrag,
                                                       const float* __restrict__ bl,
                                                       _Float16* __restrict__ h1A,
                                                       _Float16* __restrict__ h1B,
                                                       int N) {
    __shared__ __align__(16) char Ab[STRIP1 * 256];     // 16 KB
    int node0 = blockIdx.x * STRIP1;
    if (node0 >= N) return;
    int nn = min(STRIP1, N - node0);
    long long NL = N;
    const int t = threadIdx.x;
    const int lane = t & 63;
    const int wv = t >> 6;

    // ---- stage A (wave-specialized by 16B-unit group) ----
    {
        const int r = lane;
        const long long node = (long long)node0 + r;
        const bool valid = (r < nn);
        const int sw = r & 7;
        char* rowp = Ab + r * 256;

        if (wv == 0) {                       // units 0..2: k 0..23 = s/deg feats 0..23
            int dg = 1;
            if (valid) dg = row_ptr[node + 1] - row_ptr[node];
            float inv = 1.0f / (float)max(dg, 1);
            #pragma unroll
            for (int u = 0; u < 3; ++u) {
                half8 h = {0,0,0,0,0,0,0,0};
                if (valid) {
                    const float* p = spA + node * 32 + u * 8;
                    const float* q = spA + (NL + node) * 32 + u * 8;
                    float4 p0 = *(const float4*)p;
                    float4 p1 = *(const float4*)(p + 4);
                    float4 q0 = *(const float4*)q;
                    float4 q1 = *(const float4*)(q + 4);
                    h[0] = (_Float16)((p0.x + q0.x) * inv);
                    h[1] = (_Float16)((p0.y + q0.y) * inv);
                    h[2] = (_Float16)((p0.z + q0.z) * inv);
                    h[3] = (_Float16)((p0.w + q0.w) * inv);
                    h[4] = (_Float16)((p1.x + q1.x) * inv);
                    h[5] = (_Float16)((p1.y + q1.y) * inv);
                    h[6] = (_Float16)((p1.z + q1.z) * inv);
                    h[7] = (_Float16)((p1.w + q1.w) * inv);
                }
                *(half8*)(rowp + ((u ^ sw) << 4)) = h;
            }
        } else if (wv == 1) {                // u3: s 24..31; u4: sB/deg + x0..3; u5: x4..11
            int dg = 1;
            if (valid) dg = row_ptr[node + 1] - row_ptr[node];
            float inv = 1.0f / (float)max(dg, 1);
            half8 h3 = {0,0,0,0,0,0,0,0};
            half8 h4 = {0,0,0,0,0,0,0,0};
            half8 h5 = {0,0,0,0,0,0,0,0};
            if (valid) {
                const float* p = spA + node * 32 + 24;
                const float* q = spA + (NL + node) * 32 + 24;
                float4 p0 = *(const float4*)p;
                float4 p1 = *(const float4*)(p + 4);
                float4 q0 = *(const float4*)q;
                float4 q1 = *(const float4*)(q + 4);
                h3[0] = (_Float16)((p0.x + q0.x) * inv);
                h3[1] = (_Float16)((p0.y + q0.y) * inv);
                h3[2] = (_Float16)((p0.z + q0.z) * inv);
                h3[3] = (_Float16)((p0.w + q0.w) * inv);
                h3[4] = (_Float16)((p1.x + q1.x) * inv);
                h3[5] = (_Float16)((p1.y + q1.y) * inv);
                h3[6] = (_Float16)((p1.z + q1.z) * inv);
                h3[7] = (_Float16)((p1.w + q1.w) * inv);
                float4 sb0 = *(const float4*)(spB + (node << 2));
                float4 sb1 = *(const float4*)(spB + ((NL + node) << 2));
                half4 xa0 = *(const half4*)(xA + (node << 5));
                h4[0] = (_Float16)((sb0.x + sb1.x) * inv);
                h4[1] = (_Float16)((sb0.y + sb1.y) * inv);
                h4[2] = (_Float16)((sb0.z + sb1.z) * inv);
                h4[3] = (_Float16)((sb0.w + sb1.w) * inv);    // k35 = 0 (pad sums 0)
                h4[4] = xa0[0]; h4[5] = xa0[1]; h4[6] = xa0[2]; h4[7] = xa0[3];
                half4 xa1 = *(const half4*)(xA + (node << 5) + 4);
                half4 xa2 = *(const half4*)(xA + (node << 5) + 8);
                h5[0] = xa1[0]; h5[1] = xa1[1]; h5[2] = xa1[2]; h5[3] = xa1[3];
                h5[4] = xa2[0]; h5[5] = xa2[1]; h5[6] = xa2[2]; h5[7] = xa2[3];
            }
            *(half8*)(rowp + ((3 ^ sw) << 4)) = h3;
            *(half8*)(rowp + ((4 ^ sw) << 4)) = h4;
            *(half8*)(rowp + ((5 ^ sw) << 4)) = h5;
        } else if (wv == 2) {                // u6..u8: x12..19, x20..27, x28..31 + xB
            half8 h6 = {0,0,0,0,0,0,0,0};
            half8 h7 = {0,0,0,0,0,0,0,0};
            half8 h8 = {0,0,0,0,0,0,0,0};
            if (valid) {
                half4 a0 = *(const half4*)(xA + (node << 5) + 12);
                half4 a1 = *(const half4*)(xA + (node << 5) + 16);
                half4 a2 = *(const half4*)(xA + (node << 5) + 20);
                half4 a3 = *(const half4*)(xA + (node << 5) + 24);
                half4 a4 = *(const half4*)(xA + (node << 5) + 28);
                half4 b4 = *(const half4*)(xB + (node << 2));         // [3] = 0 by repack
                h6[0] = a0[0]; h6[1] = a0[1]; h6[2] = a0[2]; h6[3] = a0[3];
                h6[4] = a1[0]; h6[5] = a1[1]; h6[6] = a1[2]; h6[7] = a1[3];
                h7[0] = a2[0]; h7[1] = a2[1]; h7[2] = a2[2]; h7[3] = a2[3];
                h7[4] = a3[0]; h7[5] = a3[1]; h7[6] = a3[2]; h7[7] = a3[3];
                h8[0] = a4[0]; h8[1] = a4[1]; h8[2] = a4[2]; h8[3] = a4[3];
                h8[4] = b4[0]; h8[5] = b4[1]; h8[6] = b4[2]; h8[7] = b4[3];
            }
            *(half8*)(rowp + ((6 ^ sw) << 4)) = h6;
            *(half8*)(rowp + ((7 ^ sw) << 4)) = h7;
            *(half8*)(rowp + ((8 ^ sw) << 4)) = h8;
        } else {                             // units 9..11: zero pad
            half8 z = {0,0,0,0,0,0,0,0};
            *(half8*)(rowp + ((9  ^ sw) << 4)) = z;
            *(half8*)(rowp + ((10 ^ sw) << 4)) = z;
            *(half8*)(rowp + ((11 ^ sw) << 4)) = z;
        }
    }
    __syncthreads();

    // ---- MFMA: wave owns 16-node m-tile x 48 cols (3 n-tiles) ----
    f32x4 acc[3];
    #pragma unroll
    for (int nt = 0; nt < 3; ++nt) acc[nt] = (f32x4){0.0f, 0.0f, 0.0f, 0.0f};

    const int m0 = wv << 4;
    const int rr = m0 + (lane & 15);
    const int rsw = lane & 7;
    const int g = lane >> 4;
    const char* arow = Ab + rr * 256;

    #pragma unroll
    for (int ps = 0; ps < 2; ++ps) {
        #pragma unroll
        for (int ks = 0; ks < 3; ++ks) {
            half8 af = *(const half8*)(arow + ((((ks << 2) + g) ^ rsw) << 4));
            const _Float16* wp = wfrag + ((size_t)((ps * 3 + ks) * 3) * 64 + lane) * 8;
            #pragma unroll
            for (int nt = 0; nt < 3; ++nt) {
                half8 bf = *(const half8*)(wp + (size_t)nt * 512);
                acc[nt] = __builtin_amdgcn_mfma_f32_16x16x32_f16(af, bf, acc[nt], 0, 0, 0);
            }
        }
    }

    // ---- epilogue: relu, store h1A / h1B (D: col=lane&15, row=(lane>>4)*4+reg) ----
    const int col0 = lane & 15;
    const int rb = m0 + (g << 2);
    #pragma unroll
    for (int nt = 0; nt < 3; ++nt) {
        int col = (nt << 4) + col0;
        float bb = (col < FIN) ? bl[col] : 0.0f;
        #pragma unroll
        for (int q2 = 0; q2 < 4; ++q2) {
            int r = rb + q2;
            if (r < nn) {
                long long node = node0 + r;
                float v = fmaxf(acc[nt][q2] + bb, 0.0f);
                if (col < 32)      h1A[(node << 5) + col] = (_Float16)v;
                else if (col < 35) h1B[(node << 2) + (col - 32)] = (_Float16)v;
                else if (col == 35) h1B[(node << 2) + 3] = (_Float16)0.0f;  // pad
            }
        }
    }
}

// ---------- nu2 + pool via MFMA: h2 = (s/deg)@Wl2 + bl2 + h1@Wr2, then graph max ----------
__global__ __launch_bounds__(256) void nu2_pool_mfma_kernel(const _Float16* __restrict__ h1A,
                                                            const _Float16* __restrict__ h1B,
                                                            const float* __restrict__ spA,
                                                            const float* __restrict__ spB,
                                                            const int* __restrict__ row_ptr,
                                                            const _Float16* __restrict__ wfrag,
                                                            const float* __restrict__ bl,
                                                            const int* __restrict__ batch,
                                                            unsigned int* __restrict__ genc,
                                                            int N) {
    __shared__ __align__(16) float h_sh[STRIPM * HROW];   // 33280 B; first 16 KB doubles as A tile
    __shared__ int b_sh[STRIPM];

    int node0 = blockIdx.x * STRIPM;
    if (node0 >= N) return;
    int nn = min(STRIPM, N - node0);
    long long NL = N;

    char* Ab = (char*)h_sh;                  // A tile: [64][128] halves, swizzled 16B units
    const int t = threadIdx.x;
    const int lane = t & 63;
    const int wv = t >> 6;

    // ---- stage A (wave-specialized by kb-unit group: no divergence within a wave) ----
    {
        const int r = lane;                  // local node
        const long long node = (long long)node0 + r;
        const bool valid = (r < nn);
        const int sw = r & 7;
        char* rowp = Ab + r * 256;

        if (wv == 0) {                       // units 0..2: k 0..23 = s/deg
            int dg = 1;
            if (valid) dg = row_ptr[node + 1] - row_ptr[node];
            float inv = 1.0f / (float)max(dg, 1);
            #pragma unroll
            for (int u = 0; u < 3; ++u) {
                half8 h = {0,0,0,0,0,0,0,0};
                if (valid) {
                    const float* p = spA + node * 32 + u * 8;
                    const float* q = spA + (NL + node) * 32 + u * 8;
                    float4 p0 = *(const float4*)p;
                    float4 p1 = *(const float4*)(p + 4);
                    float4 q0 = *(const float4*)q;
                    float4 q1 = *(const float4*)(q + 4);
                    h[0] = (_Float16)((p0.x + q0.x) * inv);
                    h[1] = (_Float16)((p0.y + q0.y) * inv);
                    h[2] = (_Float16)((p0.z + q0.z) * inv);
                    h[3] = (_Float16)((p0.w + q0.w) * inv);
                    h[4] = (_Float16)((p1.x + q1.x) * inv);
                    h[5] = (_Float16)((p1.y + q1.y) * inv);
                    h[6] = (_Float16)((p1.z + q1.z) * inv);
                    h[7] = (_Float16)((p1.w + q1.w) * inv);
                }
                *(half8*)(rowp + ((u ^ sw) << 4)) = h;
            }
        } else if (wv == 1) {                // units 3..5: k 24..47 (s tail, sB + h0..3, h4..11)
            int dg = 1;
            if (valid) dg = row_ptr[node + 1] - row_ptr[node];
            float inv = 1.0f / (float)max(dg, 1);
            half8 h3 = {0,0,0,0,0,0,0,0};
            half8 h4 = {0,0,0,0,0,0,0,0};
            half8 h5 = {0,0,0,0,0,0,0,0};
            if (valid) {
                const float* p = spA + node * 32 + 24;
                const float* q = spA + (NL + node) * 32 + 24;
                float4 p0 = *(const float4*)p;
                float4 p1 = *(const float4*)(p + 4);
                float4 q0 = *(const float4*)q;
                float4 q1 = *(const float4*)(q + 4);
                h3[0] = (_Float16)((p0.x + q0.x) * inv);
                h3[1] = (_Float16)((p0.y + q0.y) * inv);
                h3[2] = (_Float16)((p0.z + q0.z) * inv);
                h3[3] = (_Float16)((p0.w + q0.w) * inv);
                h3[4] = (_Float16)((p1.x + q1.x) * inv);
                h3[5] = (_Float16)((p1.y + q1.y) * inv);
                h3[6] = (_Float16)((p1.z + q1.z) * inv);
                h3[7] = (_Float16)((p1.w + q1.w) * inv);
                float4 sb0 = *(const float4*)(spB + (node << 2));                     // pass-0 half
                float4 sb1 = *(const float4*)(spB + ((NL + node) << 2));              // pass-1 half
                half4 ha = *(const half4*)(h1A + (node << 5));
                h4[0] = (_Float16)((sb0.x + sb1.x) * inv);
                h4[1] = (_Float16)((sb0.y + sb1.y) * inv);
                h4[2] = (_Float16)((sb0.z + sb1.z) * inv);
                h4[3] = (_Float16)((sb0.w + sb1.w) * inv);                            // k35 = 0
                h4[4] = ha[0]; h4[5] = ha[1]; h4[6] = ha[2]; h4[7] = ha[3];
                half4 hb0 = *(const half4*)(h1A + (node << 5) + 4);
                half4 hb1 = *(const half4*)(h1A + (node << 5) + 8);
                h5[0] = hb0[0]; h5[1] = hb0[1]; h5[2] = hb0[2]; h5[3] = hb0[3];
                h5[4] = hb1[0]; h5[5] = hb1[1]; h5[6] = hb1[2]; h5[7] = hb1[3];
            }
            *(half8*)(rowp + ((3 ^ sw) << 4)) = h3;
            *(half8*)(rowp + ((4 ^ sw) << 4)) = h4;
            *(half8*)(rowp + ((5 ^ sw) << 4)) = h5;
        } else if (wv == 2) {                // units 6..8: h12..27, h28..34 + 0
            half8 h6 = {0,0,0,0,0,0,0,0};
            half8 h7 = {0,0,0,0,0,0,0,0};
            half8 h8 = {0,0,0,0,0,0,0,0};
            if (valid) {
                half4 a0 = *(const half4*)(h1A + (node << 5) + 12);
                half4 a1 = *(const half4*)(h1A + (node << 5) + 16);
                half4 a2 = *(const half4*)(h1A + (node << 5) + 20);
                half4 a3 = *(const half4*)(h1A + (node << 5) + 24);
                half4 a4 = *(const half4*)(h1A + (node << 5) + 28);
                half4 b4 = *(const half4*)(h1B + (node << 2));        // [3] = 0 by nu1
                h6[0] = a0[0]; h6[1] = a0[1]; h6[2] = a0[2]; h6[3] = a0[3];
                h6[4] = a1[0]; h6[5] = a1[1]; h6[6] = a1[2]; h6[7] = a1[3];
                h7[0] = a2[0]; h7[1] = a2[1]; h7[2] = a2[2]; h7[3] = a2[3];
                h7[4] = a3[0]; h7[5] = a3[1]; h7[6] = a3[2]; h7[7] = a3[3];
                h8[0] = a4[0]; h8[1] = a4[1]; h8[2] = a4[2]; h8[3] = a4[3];
                h8[4] = b4[0]; h8[5] = b4[1]; h8[6] = b4[2]; h8[7] = b4[3];
            }
            *(half8*)(rowp + ((6 ^ sw) << 4)) = h6;
            *(half8*)(rowp + ((7 ^ sw) << 4)) = h7;
            *(half8*)(rowp + ((8 ^ sw) << 4)) = h8;
        } else {                             // units 9..11: zero pad; stage batch ids
            half8 z = {0,0,0,0,0,0,0,0};
            *(half8*)(rowp + ((9  ^ sw) << 4)) = z;
            *(half8*)(rowp + ((10 ^ sw) << 4)) = z;
            *(half8*)(rowp + ((11 ^ sw) << 4)) = z;
            if (lane < nn) b_sh[lane] = batch[node0 + lane];
        }
    }
    __syncthreads();

    // ---- MFMA: each wave computes its 16-node m-tile x all 128 feats ----
    f32x4 acc[8];
    #pragma unroll
    for (int nt = 0; nt < 8; ++nt) acc[nt] = (f32x4){0.0f, 0.0f, 0.0f, 0.0f};

    const int m0 = wv << 4;
    const int rr = m0 + (lane & 15);
    const int rsw = lane & 7;                // == rr & 7 since m0 % 16 == 0
    const int g = lane >> 4;
    const char* arow = Ab + rr * 256;

    #pragma unroll
    for (int ps = 0; ps < 2; ++ps) {
        #pragma unroll
        for (int ks = 0; ks < 3; ++ks) {
            half8 af = *(const half8*)(arow + ((((ks << 2) + g) ^ rsw) << 4));
            const _Float16* wp = wfrag + ((size_t)((ps * 3 + ks) << 3) * 64 + lane) * 8;
            #pragma unroll
            for (int nt = 0; nt < 8; ++nt) {
                half8 bf = *(const half8*)(wp + (size_t)nt * 512);
                acc[nt] = __builtin_amdgcn_mfma_f32_16x16x32_f16(af, bf, acc[nt], 0, 0, 0);
            }
        }
    }
    __syncthreads();                         // A tile dead; reuse LDS for h2

    // ---- epilogue: bias + stage h2, then boundary-walk segment max ----
    const int col = lane & 15;
    const int rbase = m0 + (g << 2);         // D row = (lane>>4)*4 + reg   [m89-verified]
    #pragma unroll
    for (int nt = 0; nt < 8; ++nt) {
        float bb = bl[(nt << 4) + col];
        #pragma unroll
        for (int q2 = 0; q2 < 4; ++q2)
            h_sh[(rbase + q2) * HROW + (nt << 4) + col] = acc[nt][q2] + bb;
    }
    __syncthreads();

    const int j = t & 127;
    const int hh = t >> 7;
    int nl = hh << 5;
    int nend = min(nl + 32, nn);
    if (nl < nend) {
        int curg = b_sh[nl];
        float mx = -INFINITY;
        for (; nl < nend; ++nl) {
            float v = h_sh[nl * HROW + j];
            int gb = b_sh[nl];               // wave-uniform
            if (gb != curg) {
                atomicMax(&genc[curg * FOUT + j], enc_f32(mx));
                curg = gb;
                mx = v;
            } else {
                mx = fmaxf(mx, v);
            }
        }
        atomicMax(&genc[curg * FOUT + j], enc_f32(mx));
    }
}

// ---------- head: one block (128 threads) per graph ----------
__global__ void head_kernel(const unsigned int* __restrict__ genc,
                            const float* __restrict__ Wg1, const float* __restrict__ bg1,
                            const float* __restrict__ Wg2, const float* __restrict__ bg2,
                            const float* __restrict__ Wo,  const float* __restrict__ bo,
                            float* __restrict__ out) {
    __shared__ float a[FOUT];
    __shared__ float c[FOUT];
    __shared__ float red[2];
    int g = blockIdx.x;
    int j = threadIdx.x;

    a[j] = dec_f32(genc[g * FOUT + j]);
    __syncthreads();

    float acc = bg1[j];
    #pragma unroll 8
    for (int i = 0; i < FOUT; ++i) acc = fmaf(a[i], Wg1[i * FOUT + j], acc);
    c[j] = fmaxf(acc, 0.0f);
    __syncthreads();

    acc = bg2[j];
    #pragma unroll 8
    for (int i = 0; i < FOUT; ++i) acc = fmaf(c[i], Wg2[i * FOUT + j], acc);
    float t = fmaxf(acc, 0.0f) * Wo[j];

    #pragma unroll
    for (int off = 32; off > 0; off >>= 1) t += __shfl_down(t, off, 64);
    if ((threadIdx.x & 63) == 0) red[threadIdx.x >> 6] = t;
    __syncthreads();
    if (threadIdx.x == 0) out[g] = red[0] + red[1] + bo[0];
}

// ---------- launch ----------
extern "C" void kernel_launch(void* const* d_in, const int* in_sizes, int n_in,
                              void* d_out, int out_size, void* d_ws, size_t ws_size,
                              hipStream_t stream) {
    const float* x    = (const float*)d_in[0];
    const int*   ei   = (const int*)  d_in[1];
    const int*   batch= (const int*)  d_in[2];
    const float* Wl1  = (const float*)d_in[3];
    const float* bl1  = (const float*)d_in[4];
    const float* Wr1  = (const float*)d_in[5];
    const float* Wl2  = (const float*)d_in[6];
    const float* bl2  = (const float*)d_in[7];
    const float* Wr2  = (const float*)d_in[8];
    const float* Wg1  = (const float*)d_in[9];
    const float* bg1  = (const float*)d_in[10];
    const float* Wg2  = (const float*)d_in[11];
    const float* bg2  = (const float*)d_in[12];
    const float* Wo   = (const float*)d_in[13];
    const float* bo   = (const float*)d_in[14];
    float* out = (float*)d_out;

    const int N = in_sizes[0] / FIN;
    const int E = in_sizes[1] / 2;
    const int* src = ei;
    const int* dst = ei + E;
    const int halfN = N >> 1;

    const int nblk1 = (E + CHUNK - 1) / CHUNK;          // 391
    const int nbuck = (N + 255) >> 8;                   // 391 (<= MAXBUCK)
    const int SC = nbuck * nblk1;                       // 152881
    const int NB2 = (SC + 255) / 256;                   // 598 (<= 1024)

    // workspace layout (lifetimes: ebuf -> h1A/h1B/wfrag/wfrag1)
    char* ws = (char*)d_ws;
    size_t off = 0;
    auto alloc = [&](size_t bytes) { char* p = ws + off; off += (bytes + 255) & ~255ull; return p; };
    int*          counts  = (int*)alloc((size_t)SC * 4);
    int*          offs    = (int*)alloc((size_t)(SC + 1) * 4);
    int*          partial = (int*)alloc(1024 * 4);
    int*          row_ptr = (int*)alloc((size_t)(N + 1) * 4);
    int*          hsplit  = (int*)alloc((size_t)N * 4);
    int*          esrc    = (int*)alloc((size_t)E * 4);
    char*         regionA = (char*)alloc((size_t)E * 4);          // ebuf (12.8 MB) then h1A+h1B+wfrags
    _Float16*     xA      = (_Float16*)alloc((size_t)N * PWA * 2);
    _Float16*     xB      = (_Float16*)alloc((size_t)N * PWB * 2);
    float*        spA     = (float*)alloc((size_t)2 * N * PWA * 4);  // raw A sums, halves 0/1 (25.6 MB)
    float*        spB     = (float*)alloc((size_t)2 * N * PWB * 4);  // raw B sums, halves 0/1 (3.2 MB)
    unsigned int* genc    = (unsigned int*)alloc((size_t)NGRAPHS * FOUT * 4);
    int*       ebuf   = (int*)regionA;
    _Float16*  h1A    = (_Float16*)regionA;
    _Float16*  h1B    = (_Float16*)(regionA + (size_t)N * PWA * 2);
    _Float16*  wfrag  = (_Float16*)(regionA + (size_t)N * (PWA + PWB) * 2);            // 48 KB
    _Float16*  wfrag1 = (_Float16*)(regionA + (size_t)N * (PWA + PWB) * 2 + NFRAG * 1024); // 18 KB
    (void)ws_size; (void)n_in; (void)out_size;

    const int BS = 256;
    const int Wtot = N * 16;                             // 8N per pass x 2 passes (B folded in)
    int WS = ((Wtot / 8 + BS - 1) / BS) * BS;            // per-XCD share, 256-aligned
    const int bpx = WS / BS;                             // blocks per XCD share
    const int rpb = (N * 36 + BS - 1) / BS;              // repack items = N*(32+4)
    int nu1b = (N + STRIP1 - 1) / STRIP1;
    int nu2b = (N + STRIPM - 1) / STRIPM;

    // ---- CSR build (LDS radix, no global atomics; reused by both conv layers) ----
    hipLaunchKernelGGL(hist1_kernel, dim3(nblk1), dim3(1024), 0, stream, dst, counts, E, nblk1, nbuck);
    hipLaunchKernelGGL(partial_reduce_kernel, dim3(NB2), dim3(BS), 0, stream, counts, partial, SC);
    hipLaunchKernelGGL(scan_partials_kernel, dim3(1), dim3(1024), 0, stream, partial, NB2);
    hipLaunchKernelGGL(scan_final_kernel, dim3(NB2), dim3(BS), 0, stream, counts, partial, offs, SC);
    hipLaunchKernelGGL(scatter1_kernel, dim3(nblk1), dim3(512), 0, stream, src, dst, offs, ebuf, E, nblk1, nbuck);
    hipLaunchKernelGGL(csr2_kernel, dim3(nbuck), dim3(512), 0, stream,
                       ebuf, offs, row_ptr, hsplit, esrc, E, nblk1, nbuck, N, halfN);

    // ---- fused prep: both weight-fragment sets + genc zero (aliases dead ebuf tail) ----
    hipLaunchKernelGGL(prep_kernel, dim3(NFRAG + NFRAG1 + GZBLK), dim3(64), 0, stream,
                       Wl2, Wr2, Wl1, Wr1, wfrag, wfrag1, genc);

    // ---- conv1: fp16 repack -> two-pass gather (B folded in) -> MFMA node update ----
    hipLaunchKernelGGL(repack_kernel, dim3(rpb), dim3(BS), 0, stream, x, xA, xB, N);
    hipLaunchKernelGGL(gather2_kernel, dim3(8 * bpx), dim3(BS), 0, stream,
                       xA, xB, row_ptr, hsplit, esrc, spA, spB, N, Wtot, WS);
    hipLaunchKernelGGL(nu1_mfma_kernel, dim3(nu1b), dim3(BS), 0, stream,
                       xA, xB, spA, spB, row_ptr, wfrag1, bl1, h1A, h1B, N);

    // ---- conv2: two-pass gather over h1 -> MFMA node update + pool ----
    hipLaunchKernelGGL(gather2_kernel, dim3(8 * bpx), dim3(BS), 0, stream,
                       h1A, h1B, row_ptr, hsplit, esrc, spA, spB, N, Wtot, WS);
    hipLaunchKernelGGL(nu2_pool_mfma_kernel, dim3(nu2b), dim3(BS), 0, stream,
                       h1A, h1B, spA, spB, row_ptr, wfrag, bl2, batch, genc, N);

    // ---- head ----
    hipLaunchKernelGGL(head_kernel, dim3(NGRAPHS), dim3(FOUT), 0, stream,
                       genc, Wg1, bg1, Wg2, bg2, Wo, bo, out);
}

// Round 12
// 303.013 us; speedup vs baseline: 1.1189x; 1.0119x over previous
//
#include <hip/hip_runtime.h>
#include <hip/hip_bf16.h>
#include <math.h>

#define FIN 35
#define FOUT 128
#define NGRAPHS 512
#define PWA 32          // pass-A panel width (fp16) = 64 B rows, feats 0..31
#define PWB 4           // pass-B panel width (fp16) = 8 B rows, feats 32..34 + pad
#define STRIP1 64       // nodes per block in nu1 (MFMA: 4 waves x 16-row tiles)
#define CHUNK 8192      // edges per block in hist1/scatter1 (R7 config: best measured)
#define MAXBUCK 512     // >= ceil(N/256)
#define MAXBE 12288     // csr2 LDS edge-staging capacity (48 KB)

#define STRIPM 64       // nodes per block in nu2 (MFMA: 4 waves x 16-row tiles)
#define HROW 130        // h2 LDS row pad (floats) -> conflict-free epilogue
#define NFRAG 48        // nu2 B fragments: 2 passes (hi/lo) x 3 ksteps x 8 ntiles
#define NFRAG1 18       // nu1 B fragments: 2 passes (hi/lo) x 3 ksteps x 3 ntiles
#define GZBLK 48        // prep_kernel blocks dedicated to genc zeroing

typedef _Float16 half8 __attribute__((ext_vector_type(8)));
typedef _Float16 half4 __attribute__((ext_vector_type(4)));
typedef float f32x4 __attribute__((ext_vector_type(4)));

// ---------- helpers ----------
__device__ __forceinline__ unsigned int enc_f32(float f) {
    unsigned int u = __float_as_uint(f);
    return (u & 0x80000000u) ? ~u : (u | 0x80000000u);
}
__device__ __forceinline__ float dec_f32(unsigned int u) {
    unsigned int b = (u & 0x80000000u) ? (u ^ 0x80000000u) : ~u;
    return __uint_as_float(b);
}

// ---------- CSR build via two-level LDS radix partition (no global atomics) ----------
// R9 config (verified 306.6 us): the chain is block-latency bound; per-block wave
// count is the lever (1024-thread hist1, 512-thread scatter1/csr2 -> 2-4x shorter
// serial dependency chains, 2x waves/CU at unchanged LDS). Resubmitted as control
// after two container failures on the R10 atomic-cursor restructure.

__global__ __launch_bounds__(1024) void hist1_kernel(const int* __restrict__ dst,
                                                     int* __restrict__ counts,
                                                     int E, int nblk1, int nbuck) {
    __shared__ int h[MAXBUCK];
    int t = threadIdx.x;
    if (t < MAXBUCK) h[t] = 0;
    __syncthreads();
    int base = blockIdx.x * CHUNK;
    int end = min(base + CHUNK, E);
    for (int e = base + t; e < end; e += 1024)
        atomicAdd(&h[dst[e] >> 8], 1);
    __syncthreads();
    for (int b = t; b < nbuck; b += 1024)
        counts[b * nblk1 + blockIdx.x] = h[b];
}

__global__ void partial_reduce_kernel(const int* __restrict__ v_in, int* __restrict__ partial, int SC) {
    int i = blockIdx.x * 256 + threadIdx.x;
    int v = (i < SC) ? v_in[i] : 0;
    #pragma unroll
    for (int off = 32; off > 0; off >>= 1) v += __shfl_down(v, off, 64);
    __shared__ int w[4];
    if ((threadIdx.x & 63) == 0) w[threadIdx.x >> 6] = v;
    __syncthreads();
    if (threadIdx.x == 0) partial[blockIdx.x] = w[0] + w[1] + w[2] + w[3];
}

__global__ void scan_partials_kernel(int* __restrict__ partial, int NB) {
    __shared__ int lds[1024];
    int t = threadIdx.x;
    int v = (t < NB) ? partial[t] : 0;
    lds[t] = v;
    __syncthreads();
    for (int off = 1; off < 1024; off <<= 1) {
        int tv = (t >= off) ? lds[t - off] : 0;
        __syncthreads();
        lds[t] += tv;
        __syncthreads();
    }
    if (t < NB) partial[t] = lds[t] - v;   // exclusive
}

__global__ void scan_final_kernel(const int* __restrict__ v_in, const int* __restrict__ partial,
                                  int* __restrict__ outx, int SC) {
    __shared__ int lds[256];
    int i = blockIdx.x * 256 + threadIdx.x;
    int v = (i < SC) ? v_in[i] : 0;
    lds[threadIdx.x] = v;
    __syncthreads();
    for (int off = 1; off < 256; off <<= 1) {
        int tv = (threadIdx.x >= off) ? lds[threadIdx.x - off] : 0;
        __syncthreads();
        lds[threadIdx.x] += tv;
        __syncthreads();
    }
    int excl = lds[threadIdx.x] - v + partial[blockIdx.x];
    if (i < SC) {
        outx[i] = excl;
        if (i == SC - 1) outx[SC] = excl + v;
    }
}

// Block-local counting sort in LDS -> streaming coalesced flush (R1 win).
// 512 threads: 16 edges/thread per pass (was 32); scan phase stays 256-wide.
__global__ __launch_bounds__(512) void scatter1_kernel(const int* __restrict__ src,
                                                       const int* __restrict__ dst,
                                                       const int* __restrict__ offs,
                                                       int* __restrict__ ebuf,
                                                       int E, int nblk1, int nbuck) {
    __shared__ int hist[MAXBUCK];
    __shared__ int scn[512];
    __shared__ int gofs[MAXBUCK];        // global base - local start (dest = gofs[b] + p)
    __shared__ int cur[MAXBUCK];
    __shared__ int sv[CHUNK];            // bucket-sorted packed edges (32 KB)
    __shared__ int sd[CHUNK];            // final global destination per slot (32 KB)
    int t = threadIdx.x;
    int base = blockIdx.x * CHUNK;
    int end = min(base + CHUNK, E);

    if (t < MAXBUCK) hist[t] = 0;
    __syncthreads();
    for (int e = base + t; e < end; e += 512)
        atomicAdd(&hist[dst[e] >> 8], 1);
    __syncthreads();

    int v0 = (t < 256) ? hist[2 * t] : 0;
    int v1 = (t < 256) ? hist[2 * t + 1] : 0;
    int pair = v0 + v1;
    scn[t] = (t < 256) ? pair : 0;
    __syncthreads();
    for (int off = 1; off < 256; off <<= 1) {
        int tv = (t >= off) ? scn[t - off] : 0;
        __syncthreads();
        scn[t] += tv;
        __syncthreads();
    }
    if (t < 256) {
        int ex = scn[t] - pair;          // exclusive local start of bucket 2t
        cur[2 * t] = ex;
        cur[2 * t + 1] = ex + v0;
        int b0 = 2 * t, b1 = 2 * t + 1;
        gofs[b0] = ((b0 < nbuck) ? offs[b0 * nblk1 + blockIdx.x] : 0) - ex;
        gofs[b1] = ((b1 < nbuck) ? offs[b1 * nblk1 + blockIdx.x] : 0) - (ex + v0);
    }
    __syncthreads();

    for (int e = base + t; e < end; e += 512) {
        int d = dst[e];                  // L1/L2 hit (read in pass 1)
        int b = d >> 8;
        int p = atomicAdd(&cur[b], 1);
        sv[p] = (src[e] << 8) | (d & 255);
        sd[p] = gofs[b] + p;
    }
    __syncthreads();

    int cnt = end - base;
    for (int k = t; k < cnt; k += 512)
        ebuf[sd[k]] = sv[k];
}

// Level-2: one block per bucket; bucket edges staged in LDS. Builds row_ptr AND the
// src-half split point hsplit[n] (512 bins: node_local x (src>=N/2)). 512 threads.
__global__ __launch_bounds__(512) void csr2_kernel(const int* __restrict__ ebuf,
                                                   const int* __restrict__ offs,
                                                   int* __restrict__ row_ptr,
                                                   int* __restrict__ hsplit,
                                                   int* __restrict__ esrc,
                                                   int E, int nblk1, int nbuck, int N, int halfN) {
    __shared__ int h[512];
    __shared__ int scn[512];
    __shared__ int cur[512];
    __shared__ int e_sh[MAXBE];
    int b = blockIdx.x;
    int t = threadIdx.x;
    int bstart = offs[b * nblk1];
    int bend = (b + 1 < nbuck) ? offs[(b + 1) * nblk1] : E;
    int cnt = bend - bstart;
    bool fit = (cnt <= MAXBE);

    if (fit)
        for (int k = t; k < cnt; k += 512) e_sh[k] = ebuf[bstart + k];
    h[t] = 0;
    __syncthreads();
    for (int k = t; k < cnt; k += 512) {
        int e = fit ? e_sh[k] : ebuf[bstart + k];
        int bin = ((e & 255) << 1) | ((e >> 8) >= halfN ? 1 : 0);
        atomicAdd(&h[bin], 1);
    }
    __syncthreads();

    int v0 = (t < 256) ? h[2 * t] : 0;
    int v1 = (t < 256) ? h[2 * t + 1] : 0;
    int pair = v0 + v1;
    scn[t] = (t < 256) ? pair : 0;
    __syncthreads();
    for (int off = 1; off < 256; off <<= 1) {
        int tv = (t >= off) ? scn[t - off] : 0;
        __syncthreads();
        scn[t] += tv;
        __syncthreads();
    }
    if (t < 256) {
        int base = bstart + scn[t] - pair;   // exclusive pair prefix
        int node = (b << 8) + t;
        if (node < N) {
            row_ptr[node] = base;
            hsplit[node] = base + v0;
        }
        cur[2 * t] = base;
        cur[2 * t + 1] = base + v0;
    }
    if (b == 0 && t == 0) row_ptr[N] = E;
    __syncthreads();

    for (int k = t; k < cnt; k += 512) {
        int e = fit ? e_sh[k] : ebuf[bstart + k];
        int bin = ((e & 255) << 1) | ((e >> 8) >= halfN ? 1 : 0);
        int p = atomicAdd(&cur[bin], 1);
        esrc[p] = e >> 8;
    }
}

// ---------- repack x[N][35] -> xA[N][32] (64 B rows) + xB[N][4] (8 B rows, pad zero) ----------
__global__ void repack_kernel(const float* __restrict__ x,
                              _Float16* __restrict__ xA, _Float16* __restrict__ xB, int N) {
    int t = blockIdx.x * 256 + threadIdx.x;          // < N*36
    int NA = N * PWA;
    if (t < NA) {
        int n = t >> 5;
        int f = t & 31;
        xA[t] = (_Float16)x[(long long)n * FIN + f];
    } else if (t < NA + N * PWB) {
        int c = t - NA;
        int n = c >> 2;
        int f3 = c & 3;
        float v = (f3 < 3) ? x[(long long)n * FIN + 32 + f3] : 0.0f;
        xB[c] = (_Float16)v;
    }
}

// ---------- two-pass gather (R3 config: best measured; request-rate-floor bound) ----------
__global__ __launch_bounds__(256) void gather2_kernel(const _Float16* __restrict__ pA,
                                                      const _Float16* __restrict__ pB,
                                                      const int* __restrict__ row_ptr,
                                                      const int* __restrict__ hsplit,
                                                      const int* __restrict__ esrc,
                                                      float* __restrict__ spA,
                                                      float* __restrict__ spB,
                                                      int N, int Wtot, int WS) {
    int q = blockIdx.x & 7;
    int m = blockIdx.x >> 3;
    int w = q * WS + m * 256 + threadIdx.x;
    int wend = min((q + 1) * WS, Wtot);
    if (w >= wend) return;
    int NI = N * 8;
    int pass = w / NI;                       // 0 = A1 (low src), 1 = A2 (high src)
    int t = w - pass * NI;
    int n = t >> 3;
    int quad = (t >> 1) & 3;                 // feature octet within the 64 B row
    int q2 = t & 1;                          // sub-list half
    int b = (pass == 0) ? row_ptr[n] : hsplit[n];
    int e = (pass == 0) ? hsplit[n] : row_ptr[n + 1];
    int len = e - b;
    int k0 = b + ((len * q2) >> 1);
    int k1 = b + ((len * (q2 + 1)) >> 1);
    const _Float16* base = pA + (quad << 3);
    const bool doB = (quad == 0);

    float a0[8] = {0,0,0,0,0,0,0,0}, a1[8] = {0,0,0,0,0,0,0,0};
    float a2[8] = {0,0,0,0,0,0,0,0}, a3[8] = {0,0,0,0,0,0,0,0};
    float bb0[4] = {0,0,0,0}, bb1[4] = {0,0,0,0};
    int k = k0;
    for (; k + 4 <= k1; k += 4) {
        int s0 = esrc[k], s1 = esrc[k + 1], s2 = esrc[k + 2], s3 = esrc[k + 3];
        half8 v0 = *(const half8*)(base + ((long long)s0 << 5));
        half8 v1 = *(const half8*)(base + ((long long)s1 << 5));
        half8 v2 = *(const half8*)(base + ((long long)s2 << 5));
        half8 v3 = *(const half8*)(base + ((long long)s3 << 5));
        if (doB) {
            half4 u0 = *(const half4*)(pB + ((long long)s0 << 2));
            half4 u1 = *(const half4*)(pB + ((long long)s1 << 2));
            half4 u2 = *(const half4*)(pB + ((long long)s2 << 2));
            half4 u3 = *(const half4*)(pB + ((long long)s3 << 2));
            #pragma unroll
            for (int i = 0; i < 4; ++i) {
                bb0[i] += (float)u0[i] + (float)u2[i];
                bb1[i] += (float)u1[i] + (float)u3[i];
            }
        }
        #pragma unroll
        for (int i = 0; i < 8; ++i) {
            a0[i] += (float)v0[i];
            a1[i] += (float)v1[i];
            a2[i] += (float)v2[i];
            a3[i] += (float)v3[i];
        }
    }
    for (; k < k1; ++k) {
        int s = esrc[k];
        half8 v = *(const half8*)(base + ((long long)s << 5));
        if (doB) {
            half4 u = *(const half4*)(pB + ((long long)s << 2));
            #pragma unroll
            for (int i = 0; i < 4; ++i) bb0[i] += (float)u[i];
        }
        #pragma unroll
        for (int i = 0; i < 8; ++i) a0[i] += (float)v[i];
    }

    float s[8];
    #pragma unroll
    for (int i = 0; i < 8; ++i) {
        float p = (a0[i] + a1[i]) + (a2[i] + a3[i]);
        p += __shfl_xor(p, 1, 64);           // combine the two q2 halves
        s[i] = p;
    }
    if (q2 == 0) {                           // raw sums, no division
        float* outp = spA + ((long long)pass * N + n) * PWA + (quad << 3);
        float4 r0, r1;
        r0.x = s[0]; r0.y = s[1]; r0.z = s[2]; r0.w = s[3];
        r1.x = s[4]; r1.y = s[5]; r1.z = s[6]; r1.w = s[7];
        *(float4*)outp = r0;
        *(float4*)(outp + 4) = r1;
    }
    if (doB) {
        float bs[4];
        #pragma unroll
        for (int i = 0; i < 4; ++i) {
            float p = bb0[i] + bb1[i];
            p += __shfl_xor(p, 1, 64);       // lanes t and t^1 both have quad==0
            bs[i] = p;
        }
        if (q2 == 0) {
            float4 r;
            r.x = bs[0]; r.y = bs[1]; r.z = bs[2]; r.w = bs[3];
            *(float4*)(spB + (((long long)pass * N + n) << 2)) = r;
        }
    }
}

// ---------- fused prep: nu2 wfrag (blocks 0..47), nu1 wfrag1 (48..65), genc zero ----------
// B rows nu2 (K=96): 0..34 = Wl2, 35 = 0, 36..70 = Wr2, 71..95 = 0.
// B rows nu1: same layout with Wl1/Wr1 (35 cols; cols >= 35 zero).
// pass 0 = fp16(w), pass 1 = fp16(w - fp16(w)) -> two MFMA accumulations, fp32-exact.
__global__ void prep_kernel(const float* __restrict__ Wl2, const float* __restrict__ Wr2,
                            const float* __restrict__ Wl1, const float* __restrict__ Wr1,
                            _Float16* __restrict__ wfrag, _Float16* __restrict__ wfrag1,
                            unsigned int* __restrict__ genc) {
    int f = blockIdx.x;
    int l = threadIdx.x;       // 0..63
    if (f < NFRAG) {           // nu2 fragments
        int ps = f / 24;
        int rem = f % 24;
        int ks = rem >> 3;
        int nt = rem & 7;
        int n = nt * 16 + (l & 15);
        int kb = ks * 32 + ((l >> 4) << 3);
        half8 o;
        #pragma unroll
        for (int e = 0; e < 8; ++e) {
            int k = kb + e;
            float v = 0.0f;
            if (k < 35) v = Wl2[k * FOUT + n];
            else if (k >= 36 && k < 71) v = Wr2[(k - 36) * FOUT + n];
            _Float16 hi = (_Float16)v;
            o[e] = ps ? (_Float16)(v - (float)hi) : hi;
        }
        *(half8*)(wfrag + ((size_t)f * 64 + l) * 8) = o;
    } else if (f < NFRAG + NFRAG1) {    // nu1 fragments
        int f1 = f - NFRAG;
        int ps = f1 / 9;
        int rem = f1 % 9;
        int ks = rem / 3;
        int nt = rem % 3;
        int n = nt * 16 + (l & 15);
        int kb = ks * 32 + ((l >> 4) << 3);
        half8 o;
        #pragma unroll
        for (int e = 0; e < 8; ++e) {
            int k = kb + e;
            float v = 0.0f;
            if (n < FIN) {
                if (k < 35) v = Wl1[k * FIN + n];
                else if (k >= 36 && k < 71) v = Wr1[(k - 36) * FIN + n];
            }
            _Float16 hi = (_Float16)v;
            o[e] = ps ? (_Float16)(v - (float)hi) : hi;
        }
        *(half8*)(wfrag1 + ((size_t)f1 * 64 + l) * 8) = o;
    } else {                            // zero genc (replaces hipMemsetAsync)
        int idx = (f - NFRAG - NFRAG1) * 64 + l;
        for (int i = idx; i < NGRAPHS * FOUT; i += GZBLK * 64)
            genc[i] = 0u;
    }
}

// ---------- nu1 via MFMA: h1 = relu((s/deg)@Wl1 + bl1 + x@Wr1) ----------
__global__ __launch_bounds__(256) void nu1_mfma_kernel(const _Float16* __restrict__ xA,
                                                       const _Float16* __restrict__ xB,
                                                       const float* __restrict__ spA,
                                                       const float* __restrict__ spB,
                                                       const int* __restrict__ row_ptr,
                                                       const _Float16* __restrict__ wfrag,
                                                       const float* __restrict__ bl,
                                                       _Float16* __restrict__ h1A,
                                                       _Float16* __restrict__ h1B,
                                                       int N) {
    __shared__ __align__(16) char Ab[STRIP1 * 256];     // 16 KB
    int node0 = blockIdx.x * STRIP1;
    if (node0 >= N) return;
    int nn = min(STRIP1, N - node0);
    long long NL = N;
    const int t = threadIdx.x;
    const int lane = t & 63;
    const int wv = t >> 6;

    // ---- stage A (wave-specialized by 16B-unit group) ----
    {
        const int r = lane;
        const long long node = (long long)node0 + r;
        const bool valid = (r < nn);
        const int sw = r & 7;
        char* rowp = Ab + r * 256;

        if (wv == 0) {                       // units 0..2: k 0..23 = s/deg feats 0..23
            int dg = 1;
            if (valid) dg = row_ptr[node + 1] - row_ptr[node];
            float inv = 1.0f / (float)max(dg, 1);
            #pragma unroll
            for (int u = 0; u < 3; ++u) {
                half8 h = {0,0,0,0,0,0,0,0};
                if (valid) {
                    const float* p = spA + node * 32 + u * 8;
                    const float* q = spA + (NL + node) * 32 + u * 8;
                    float4 p0 = *(const float4*)p;
                    float4 p1 = *(const float4*)(p + 4);
                    float4 q0 = *(const float4*)q;
                    float4 q1 = *(const float4*)(q + 4);
                    h[0] = (_Float16)((p0.x + q0.x) * inv);
                    h[1] = (_Float16)((p0.y + q0.y) * inv);
                    h[2] = (_Float16)((p0.z + q0.z) * inv);
                    h[3] = (_Float16)((p0.w + q0.w) * inv);
                    h[4] = (_Float16)((p1.x + q1.x) * inv);
                    h[5] = (_Float16)((p1.y + q1.y) * inv);
                    h[6] = (_Float16)((p1.z + q1.z) * inv);
                    h[7] = (_Float16)((p1.w + q1.w) * inv);
                }
                *(half8*)(rowp + ((u ^ sw) << 4)) = h;
            }
        } else if (wv == 1) {                // u3: s 24..31; u4: sB/deg + x0..3; u5: x4..11
            int dg = 1;
            if (valid) dg = row_ptr[node + 1] - row_ptr[node];
            float inv = 1.0f / (float)max(dg, 1);
            half8 h3 = {0,0,0,0,0,0,0,0};
            half8 h4 = {0,0,0,0,0,0,0,0};
            half8 h5 = {0,0,0,0,0,0,0,0};
            if (valid) {
                const float* p = spA + node * 32 + 24;
                const float* q = spA + (NL + node) * 32 + 24;
                float4 p0 = *(const float4*)p;
                float4 p1 = *(const float4*)(p + 4);
                float4 q0 = *(const float4*)q;
                float4 q1 = *(const float4*)(q + 4);
                h3[0] = (_Float16)((p0.x + q0.x) * inv);
                h3[1] = (_Float16)((p0.y + q0.y) * inv);
                h3[2] = (_Float16)((p0.z + q0.z) * inv);
                h3[3] = (_Float16)((p0.w + q0.w) * inv);
                h3[4] = (_Float16)((p1.x + q1.x) * inv);
                h3[5] = (_Float16)((p1.y + q1.y) * inv);
                h3[6] = (_Float16)((p1.z + q1.z) * inv);
                h3[7] = (_Float16)((p1.w + q1.w) * inv);
                float4 sb0 = *(const float4*)(spB + (node << 2));
                float4 sb1 = *(const float4*)(spB + ((NL + node) << 2));
                half4 xa0 = *(const half4*)(xA + (node << 5));
                h4[0] = (_Float16)((sb0.x + sb1.x) * inv);
                h4[1] = (_Float16)((sb0.y + sb1.y) * inv);
                h4[2] = (_Float16)((sb0.z + sb1.z) * inv);
                h4[3] = (_Float16)((sb0.w + sb1.w) * inv);    // k35 = 0 (pad sums 0)
                h4[4] = xa0[0]; h4[5] = xa0[1]; h4[6] = xa0[2]; h4[7] = xa0[3];
                half4 xa1 = *(const half4*)(xA + (node << 5) + 4);
                half4 xa2 = *(const half4*)(xA + (node << 5) + 8);
                h5[0] = xa1[0]; h5[1] = xa1[1]; h5[2] = xa1[2]; h5[3] = xa1[3];
                h5[4] = xa2[0]; h5[5] = xa2[1]; h5[6] = xa2[2]; h5[7] = xa2[3];
            }
            *(half8*)(rowp + ((3 ^ sw) << 4)) = h3;
            *(half8*)(rowp + ((4 ^ sw) << 4)) = h4;
            *(half8*)(rowp + ((5 ^ sw) << 4)) = h5;
        } else if (wv == 2) {                // u6..u8: x12..19, x20..27, x28..31 + xB
            half8 h6 = {0,0,0,0,0,0,0,0};
            half8 h7 = {0,0,0,0,0,0,0,0};
            half8 h8 = {0,0,0,0,0,0,0,0};
            if (valid) {
                half4 a0 = *(const half4*)(xA + (node << 5) + 12);
                half4 a1 = *(const half4*)(xA + (node << 5) + 16);
                half4 a2 = *(const half4*)(xA + (node << 5) + 20);
                half4 a3 = *(const half4*)(xA + (node << 5) + 24);
                half4 a4 = *(const half4*)(xA + (node << 5) + 28);
                half4 b4 = *(const half4*)(xB + (node << 2));         // [3] = 0 by repack
                h6[0] = a0[0]; h6[1] = a0[1]; h6[2] = a0[2]; h6[3] = a0[3];
                h6[4] = a1[0]; h6[5] = a1[1]; h6[6] = a1[2]; h6[7] = a1[3];
                h7[0] = a2[0]; h7[1] = a2[1]; h7[2] = a2[2]; h7[3] = a2[3];
                h7[4] = a3[0]; h7[5] = a3[1]; h7[6] = a3[2]; h7[7] = a3[3];
                h8[0] = a4[0]; h8[1] = a4[1]; h8[2] = a4[2]; h8[3] = a4[3];
                h8[4] = b4[0]; h8[5] = b4[1]; h8[6] = b4[2]; h8[7] = b4[3];
            }
            *(half8*)(rowp + ((6 ^ sw) << 4)) = h6;
            *(half8*)(rowp + ((7 ^ sw) << 4)) = h7;
            *(half8*)(rowp + ((8 ^ sw) << 4)) = h8;
        } else {                             // units 9..11: zero pad
            half8 z = {0,0,0,0,0,0,0,0};
            *(half8*)(rowp + ((9  ^ sw) << 4)) = z;
            *(half8*)(rowp + ((10 ^ sw) << 4)) = z;
            *(half8*)(rowp + ((11 ^ sw) << 4)) = z;
        }
    }
    __syncthreads();

    // ---- MFMA: wave owns 16-node m-tile x 48 cols (3 n-tiles) ----
    f32x4 acc[3];
    #pragma unroll
    for (int nt = 0; nt < 3; ++nt) acc[nt] = (f32x4){0.0f, 0.0f, 0.0f, 0.0f};

    const int m0 = wv << 4;
    const int rr = m0 + (lane & 15);
    const int rsw = lane & 7;
    const int g = lane >> 4;
    const char* arow = Ab + rr * 256;

    #pragma unroll
    for (int ps = 0; ps < 2; ++ps) {
        #pragma unroll
        for (int ks = 0; ks < 3; ++ks) {
            half8 af = *(const half8*)(arow + ((((ks << 2) + g) ^ rsw) << 4));
            const _Float16* wp = wfrag + ((size_t)((ps * 3 + ks) * 3) * 64 + lane) * 8;
            #pragma unroll
            for (int nt = 0; nt < 3; ++nt) {
                half8 bf = *(const half8*)(wp + (size_t)nt * 512);
                acc[nt] = __builtin_amdgcn_mfma_f32_16x16x32_f16(af, bf, acc[nt], 0, 0, 0);
            }
        }
    }

    // ---- epilogue: relu, store h1A / h1B (D: col=lane&15, row=(lane>>4)*4+reg) ----
    const int col0 = lane & 15;
    const int rb = m0 + (g << 2);
    #pragma unroll
    for (int nt = 0; nt < 3; ++nt) {
        int col = (nt << 4) + col0;
        float bb = (col < FIN) ? bl[col] : 0.0f;
        #pragma unroll
        for (int q2 = 0; q2 < 4; ++q2) {
            int r = rb + q2;
            if (r < nn) {
                long long node = node0 + r;
                float v = fmaxf(acc[nt][q2] + bb, 0.0f);
                if (col < 32)      h1A[(node << 5) + col] = (_Float16)v;
                else if (col < 35) h1B[(node << 2) + (col - 32)] = (_Float16)v;
                else if (col == 35) h1B[(node << 2) + 3] = (_Float16)0.0f;  // pad
            }
        }
    }
}

// ---------- nu2 + pool via MFMA: h2 = (s/deg)@Wl2 + bl2 + h1@Wr2, then graph max ----------
__global__ __launch_bounds__(256) void nu2_pool_mfma_kernel(const _Float16* __restrict__ h1A,
                                                            const _Float16* __restrict__ h1B,
                                                            const float* __restrict__ spA,
                                                            const float* __restrict__ spB,
                                                            const int* __restrict__ row_ptr,
                                                            const _Float16* __restrict__ wfrag,
                                                            const float* __restrict__ bl,
                                                            const int* __restrict__ batch,
                                                            unsigned int* __restrict__ genc,
                                                            int N) {
    __shared__ __align__(16) float h_sh[STRIPM * HROW];   // 33280 B; first 16 KB doubles as A tile
    __shared__ int b_sh[STRIPM];

    int node0 = blockIdx.x * STRIPM;
    if (node0 >= N) return;
    int nn = min(STRIPM, N - node0);
    long long NL = N;

    char* Ab = (char*)h_sh;                  // A tile: [64][128] halves, swizzled 16B units
    const int t = threadIdx.x;
    const int lane = t & 63;
    const int wv = t >> 6;

    // ---- stage A (wave-specialized by kb-unit group: no divergence within a wave) ----
    {
        const int r = lane;                  // local node
        const long long node = (long long)node0 + r;
        const bool valid = (r < nn);
        const int sw = r & 7;
        char* rowp = Ab + r * 256;

        if (wv == 0) {                       // units 0..2: k 0..23 = s/deg
            int dg = 1;
            if (valid) dg = row_ptr[node + 1] - row_ptr[node];
            float inv = 1.0f / (float)max(dg, 1);
            #pragma unroll
            for (int u = 0; u < 3; ++u) {
                half8 h = {0,0,0,0,0,0,0,0};
                if (valid) {
                    const float* p = spA + node * 32 + u * 8;
                    const float* q = spA + (NL + node) * 32 + u * 8;
                    float4 p0 = *(const float4*)p;
                    float4 p1 = *(const float4*)(p + 4);
                    float4 q0 = *(const float4*)q;
                    float4 q1 = *(const float4*)(q + 4);
                    h[0] = (_Float16)((p0.x + q0.x) * inv);
                    h[1] = (_Float16)((p0.y + q0.y) * inv);
                    h[2] = (_Float16)((p0.z + q0.z) * inv);
                    h[3] = (_Float16)((p0.w + q0.w) * inv);
                    h[4] = (_Float16)((p1.x + q1.x) * inv);
                    h[5] = (_Float16)((p1.y + q1.y) * inv);
                    h[6] = (_Float16)((p1.z + q1.z) * inv);
                    h[7] = (_Float16)((p1.w + q1.w) * inv);
                }
                *(half8*)(rowp + ((u ^ sw) << 4)) = h;
            }
        } else if (wv == 1) {                // units 3..5: k 24..47 (s tail, sB + h0..3, h4..11)
            int dg = 1;
            if (valid) dg = row_ptr[node + 1] - row_ptr[node];
            float inv = 1.0f / (float)max(dg, 1);
            half8 h3 = {0,0,0,0,0,0,0,0};
            half8 h4 = {0,0,0,0,0,0,0,0};
            half8 h5 = {0,0,0,0,0,0,0,0};
            if (valid) {
                const float* p = spA + node * 32 + 24;
                const float* q = spA + (NL + node) * 32 + 24;
                float4 p0 = *(const float4*)p;
                float4 p1 = *(const float4*)(p + 4);
                float4 q0 = *(const float4*)q;
                float4 q1 = *(const float4*)(q + 4);
                h3[0] = (_Float16)((p0.x + q0.x) * inv);
                h3[1] = (_Float16)((p0.y + q0.y) * inv);
                h3[2] = (_Float16)((p0.z + q0.z) * inv);
                h3[3] = (_Float16)((p0.w + q0.w) * inv);
                h3[4] = (_Float16)((p1.x + q1.x) * inv);
                h3[5] = (_Float16)((p1.y + q1.y) * inv);
                h3[6] = (_Float16)((p1.z + q1.z) * inv);
                h3[7] = (_Float16)((p1.w + q1.w) * inv);
                float4 sb0 = *(const float4*)(spB + (node << 2));                     // pass-0 half
                float4 sb1 = *(const float4*)(spB + ((NL + node) << 2));              // pass-1 half
                half4 ha = *(const half4*)(h1A + (node << 5));
                h4[0] = (_Float16)((sb0.x + sb1.x) * inv);
                h4[1] = (_Float16)((sb0.y + sb1.y) * inv);
                h4[2] = (_Float16)((sb0.z + sb1.z) * inv);
                h4[3] = (_Float16)((sb0.w + sb1.w) * inv);                            // k35 = 0
                h4[4] = ha[0]; h4[5] = ha[1]; h4[6] = ha[2]; h4[7] = ha[3];
                half4 hb0 = *(const half4*)(h1A + (node << 5) + 4);
                half4 hb1 = *(const half4*)(h1A + (node << 5) + 8);
                h5[0] = hb0[0]; h5[1] = hb0[1]; h5[2] = hb0[2]; h5[3] = hb0[3];
                h5[4] = hb1[0]; h5[5] = hb1[1]; h5[6] = hb1[2]; h5[7] = hb1[3];
            }
            *(half8*)(rowp + ((3 ^ sw) << 4)) = h3;
            *(half8*)(rowp + ((4 ^ sw) << 4)) = h4;
            *(half8*)(rowp + ((5 ^ sw) << 4)) = h5;
        } else if (wv == 2) {                // units 6..8: h12..27, h28..34 + 0
            half8 h6 = {0,0,0,0,0,0,0,0};
            half8 h7 = {0,0,0,0,0,0,0,0};
            half8 h8 = {0,0,0,0,0,0,0,0};
            if (valid) {
                half4 a0 = *(const half4*)(h1A + (node << 5) + 12);
                half4 a1 = *(const half4*)(h1A + (node << 5) + 16);
                half4 a2 = *(const half4*)(h1A + (node << 5) + 20);
                half4 a3 = *(const half4*)(h1A + (node << 5) + 24);
                half4 a4 = *(const half4*)(h1A + (node << 5) + 28);
                half4 b4 = *(const half4*)(h1B + (node << 2));        // [3] = 0 by nu1
                h6[0] = a0[0]; h6[1] = a0[1]; h6[2] = a0[2]; h6[3] = a0[3];
                h6[4] = a1[0]; h6[5] = a1[1]; h6[6] = a1[2]; h6[7] = a1[3];
                h7[0] = a2[0]; h7[1] = a2[1]; h7[2] = a2[2]; h7[3] = a2[3];
                h7[4] = a3[0]; h7[5] = a3[1]; h7[6] = a3[2]; h7[7] = a3[3];
                h8[0] = a4[0]; h8[1] = a4[1]; h8[2] = a4[2]; h8[3] = a4[3];
                h8[4] = b4[0]; h8[5] = b4[1]; h8[6] = b4[2]; h8[7] = b4[3];
            }
            *(half8*)(rowp + ((6 ^ sw) << 4)) = h6;
            *(half8*)(rowp + ((7 ^ sw) << 4)) = h7;
            *(half8*)(rowp + ((8 ^ sw) << 4)) = h8;
        } else {                             // units 9..11: zero pad; stage batch ids
            half8 z = {0,0,0,0,0,0,0,0};
            *(half8*)(rowp + ((9  ^ sw) << 4)) = z;
            *(half8*)(rowp + ((10 ^ sw) << 4)) = z;
            *(half8*)(rowp + ((11 ^ sw) << 4)) = z;
            if (lane < nn) b_sh[lane] = batch[node0 + lane];
        }
    }
    __syncthreads();

    // ---- MFMA: each wave computes its 16-node m-tile x all 128 feats ----
    f32x4 acc[8];
    #pragma unroll
    for (int nt = 0; nt < 8; ++nt) acc[nt] = (f32x4){0.0f, 0.0f, 0.0f, 0.0f};

    const int m0 = wv << 4;
    const int rr = m0 + (lane & 15);
    const int rsw = lane & 7;                // == rr & 7 since m0 % 16 == 0
    const int g = lane >> 4;
    const char* arow = Ab + rr * 256;

    #pragma unroll
    for (int ps = 0; ps < 2; ++ps) {
        #pragma unroll
        for (int ks = 0; ks < 3; ++ks) {
            half8 af = *(const half8*)(arow + ((((ks << 2) + g) ^ rsw) << 4));
            const _Float16* wp = wfrag + ((size_t)((ps * 3 + ks) << 3) * 64 + lane) * 8;
            #pragma unroll
            for (int nt = 0; nt < 8; ++nt) {
                half8 bf = *(const half8*)(wp + (size_t)nt * 512);
                acc[nt] = __builtin_amdgcn_mfma_f32_16x16x32_f16(af, bf, acc[nt], 0, 0, 0);
            }
        }
    }
    __syncthreads();                         // A tile dead; reuse LDS for h2

    // ---- epilogue: bias + stage h2, then boundary-walk segment max ----
    const int col = lane & 15;
    const int rbase = m0 + (g << 2);         // D row = (lane>>4)*4 + reg   [m89-verified]
    #pragma unroll
    for (int nt = 0; nt < 8; ++nt) {
        float bb = bl[(nt << 4) + col];
        #pragma unroll
        for (int q2 = 0; q2 < 4; ++q2)
            h_sh[(rbase + q2) * HROW + (nt << 4) + col] = acc[nt][q2] + bb;
    }
    __syncthreads();

    const int j = t & 127;
    const int hh = t >> 7;
    int nl = hh << 5;
    int nend = min(nl + 32, nn);
    if (nl < nend) {
        int curg = b_sh[nl];
        float mx = -INFINITY;
        for (; nl < nend; ++nl) {
            float v = h_sh[nl * HROW + j];
            int gb = b_sh[nl];               // wave-uniform
            if (gb != curg) {
                atomicMax(&genc[curg * FOUT + j], enc_f32(mx));
                curg = gb;
                mx = v;
            } else {
                mx = fmaxf(mx, v);
            }
        }
        atomicMax(&genc[curg * FOUT + j], enc_f32(mx));
    }
}

// ---------- head: one block (128 threads) per graph ----------
__global__ void head_kernel(const unsigned int* __restrict__ genc,
                            const float* __restrict__ Wg1, const float* __restrict__ bg1,
                            const float* __restrict__ Wg2, const float* __restrict__ bg2,
                            const float* __restrict__ Wo,  const float* __restrict__ bo,
                            float* __restrict__ out) {
    __shared__ float a[FOUT];
    __shared__ float c[FOUT];
    __shared__ float red[2];
    int g = blockIdx.x;
    int j = threadIdx.x;

    a[j] = dec_f32(genc[g * FOUT + j]);
    __syncthreads();

    float acc = bg1[j];
    #pragma unroll 8
    for (int i = 0; i < FOUT; ++i) acc = fmaf(a[i], Wg1[i * FOUT + j], acc);
    c[j] = fmaxf(acc, 0.0f);
    __syncthreads();

    acc = bg2[j];
    #pragma unroll 8
    for (int i = 0; i < FOUT; ++i) acc = fmaf(c[i], Wg2[i * FOUT + j], acc);
    float t = fmaxf(acc, 0.0f) * Wo[j];

    #pragma unroll
    for (int off = 32; off > 0; off >>= 1) t += __shfl_down(t, off, 64);
    if ((threadIdx.x & 63) == 0) red[threadIdx.x >> 6] = t;
    __syncthreads();
    if (threadIdx.x == 0) out[g] = red[0] + red[1] + bo[0];
}

// ---------- launch ----------
extern "C" void kernel_launch(void* const* d_in, const int* in_sizes, int n_in,
                              void* d_out, int out_size, void* d_ws, size_t ws_size,
                              hipStream_t stream) {
    const float* x    = (const float*)d_in[0];
    const int*   ei   = (const int*)  d_in[1];
    const int*   batch= (const int*)  d_in[2];
    const float* Wl1  = (const float*)d_in[3];
    const float* bl1  = (const float*)d_in[4];
    const float* Wr1  = (const float*)d_in[5];
    const float* Wl2  = (const float*)d_in[6];
    const float* bl2  = (const float*)d_in[7];
    const float* Wr2  = (const float*)d_in[8];
    const float* Wg1  = (const float*)d_in[9];
    const float* bg1  = (const float*)d_in[10];
    const float* Wg2  = (const float*)d_in[11];
    const float* bg2  = (const float*)d_in[12];
    const float* Wo   = (const float*)d_in[13];
    const float* bo   = (const float*)d_in[14];
    float* out = (float*)d_out;

    const int N = in_sizes[0] / FIN;
    const int E = in_sizes[1] / 2;
    const int* src = ei;
    const int* dst = ei + E;
    const int halfN = N >> 1;

    const int nblk1 = (E + CHUNK - 1) / CHUNK;          // 391
    const int nbuck = (N + 255) >> 8;                   // 391 (<= MAXBUCK)
    const int SC = nbuck * nblk1;                       // 152881
    const int NB2 = (SC + 255) / 256;                   // 598 (<= 1024)

    // workspace layout (lifetimes: ebuf -> h1A/h1B/wfrag/wfrag1)
    char* ws = (char*)d_ws;
    size_t off = 0;
    auto alloc = [&](size_t bytes) { char* p = ws + off; off += (bytes + 255) & ~255ull; return p; };
    int*          counts  = (int*)alloc((size_t)SC * 4);
    int*          offs    = (int*)alloc((size_t)(SC + 1) * 4);
    int*          partial = (int*)alloc(1024 * 4);
    int*          row_ptr = (int*)alloc((size_t)(N + 1) * 4);
    int*          hsplit  = (int*)alloc((size_t)N * 4);
    int*          esrc    = (int*)alloc((size_t)E * 4);
    char*         regionA = (char*)alloc((size_t)E * 4);          // ebuf (12.8 MB) then h1A+h1B+wfrags
    _Float16*     xA      = (_Float16*)alloc((size_t)N * PWA * 2);
    _Float16*     xB      = (_Float16*)alloc((size_t)N * PWB * 2);
    float*        spA     = (float*)alloc((size_t)2 * N * PWA * 4);  // raw A sums, halves 0/1 (25.6 MB)
    float*        spB     = (float*)alloc((size_t)2 * N * PWB * 4);  // raw B sums, halves 0/1 (3.2 MB)
    unsigned int* genc    = (unsigned int*)alloc((size_t)NGRAPHS * FOUT * 4);
    int*       ebuf   = (int*)regionA;
    _Float16*  h1A    = (_Float16*)regionA;
    _Float16*  h1B    = (_Float16*)(regionA + (size_t)N * PWA * 2);
    _Float16*  wfrag  = (_Float16*)(regionA + (size_t)N * (PWA + PWB) * 2);            // 48 KB
    _Float16*  wfrag1 = (_Float16*)(regionA + (size_t)N * (PWA + PWB) * 2 + NFRAG * 1024); // 18 KB
    (void)ws_size; (void)n_in; (void)out_size;

    const int BS = 256;
    const int Wtot = N * 16;                             // 8N per pass x 2 passes (B folded in)
    int WS = ((Wtot / 8 + BS - 1) / BS) * BS;            // per-XCD share, 256-aligned
    const int bpx = WS / BS;                             // blocks per XCD share
    const int rpb = (N * 36 + BS - 1) / BS;              // repack items = N*(32+4)
    int nu1b = (N + STRIP1 - 1) / STRIP1;
    int nu2b = (N + STRIPM - 1) / STRIPM;

    // ---- CSR build (LDS radix, no global atomics; reused by both conv layers) ----
    hipLaunchKernelGGL(hist1_kernel, dim3(nblk1), dim3(1024), 0, stream, dst, counts, E, nblk1, nbuck);
    hipLaunchKernelGGL(partial_reduce_kernel, dim3(NB2), dim3(BS), 0, stream, counts, partial, SC);
    hipLaunchKernelGGL(scan_partials_kernel, dim3(1), dim3(1024), 0, stream, partial, NB2);
    hipLaunchKernelGGL(scan_final_kernel, dim3(NB2), dim3(BS), 0, stream, counts, partial, offs, SC);
    hipLaunchKernelGGL(scatter1_kernel, dim3(nblk1), dim3(512), 0, stream, src, dst, offs, ebuf, E, nblk1, nbuck);
    hipLaunchKernelGGL(csr2_kernel, dim3(nbuck), dim3(512), 0, stream,
                       ebuf, offs, row_ptr, hsplit, esrc, E, nblk1, nbuck, N, halfN);

    // ---- fused prep: both weight-fragment sets + genc zero (aliases dead ebuf tail) ----
    hipLaunchKernelGGL(prep_kernel, dim3(NFRAG + NFRAG1 + GZBLK), dim3(64), 0, stream,
                       Wl2, Wr2, Wl1, Wr1, wfrag, wfrag1, genc);

    // ---- conv1: fp16 repack -> two-pass gather (B folded in) -> MFMA node update ----
    hipLaunchKernelGGL(repack_kernel, dim3(rpb), dim3(BS), 0, stream, x, xA, xB, N);
    hipLaunchKernelGGL(gather2_kernel, dim3(8 * bpx), dim3(BS), 0, stream,
                       xA, xB, row_ptr, hsplit, esrc, spA, spB, N, Wtot, WS);
    hipLaunchKernelGGL(nu1_mfma_kernel, dim3(nu1b), dim3(BS), 0, stream,
                       xA, xB, spA, spB, row_ptr, wfrag1, bl1, h1A, h1B, N);

    // ---- conv2: two-pass gather over h1 -> MFMA node update + pool ----
    hipLaunchKernelGGL(gather2_kernel, dim3(8 * bpx), dim3(BS), 0, stream,
                       h1A, h1B, row_ptr, hsplit, esrc, spA, spB, N, Wtot, WS);
    hipLaunchKernelGGL(nu2_pool_mfma_kernel, dim3(nu2b), dim3(BS), 0, stream,
                       h1A, h1B, spA, spB, row_ptr, wfrag, bl2, batch, genc, N);

    // ---- head ----
    hipLaunchKernelGGL(head_kernel, dim3(NGRAPHS), dim3(FOUT), 0, stream,
                       genc, Wg1, bg1, Wg2, bg2, Wo, bo, out);
}